// Round 20
// baseline (315.470 us; speedup 1.0000x reference)
//
#include <hip/hip_runtime.h>
#include <hip/hip_bf16.h>
#include <cstdint>

typedef unsigned short u16;
typedef unsigned int u32;
typedef __attribute__((__ext_vector_type__(4))) float f32x4;
typedef __attribute__((__ext_vector_type__(4))) u32 u32x4;
typedef __attribute__((__ext_vector_type__(2))) u32 u32x2;
typedef __attribute__((__ext_vector_type__(8))) __bf16 bf16x8;

#define DEV __device__ __forceinline__

static constexpr int Tt = 1024, Dd = 1024;
static constexpr int Mrows = 4096;  // B*T

DEV u16 f2bf(float f) {
  u32 u = __float_as_uint(f);
  u += 0x7fffu + ((u >> 16) & 1u);
  return (u16)(u >> 16);
}
DEV float bf2f(u16 h) { return __uint_as_float(((u32)h) << 16); }

DEV void gload_lds16(const void* g, void* l) {
  __builtin_amdgcn_global_load_lds(
      (__attribute__((address_space(1))) void*)(g),
      (__attribute__((address_space(3))) void*)(l), 16, 0, 0);
}

// 16B-unit XOR swizzle for pb rows (write+read must agree); col in u16 units.
DEV int swz8(int row, int lq) { return (lq ^ ((row >> 3) & 3)) * 8; }

// ---------------- fused transpose fp32 [K,N] -> bf16 [N,K], 11 matrices ----------------
struct TransDesc {
  const float* src[11];
  u16* dst[11];
  int K[11];
  int N[11];
};

__global__ __launch_bounds__(256) void k_transpose_all(TransDesc td) {
  int z = blockIdx.z;
  int K = td.K[z], N = td.N[z];
  int n0 = blockIdx.x * 32, k0 = blockIdx.y * 32;
  if (n0 >= N || k0 >= K) return;
  const float* W = td.src[z];
  u16* Wt = td.dst[z];
  __shared__ float tile[32][33];
  int c = threadIdx.x & 31, r0 = threadIdx.x >> 5;
#pragma unroll
  for (int i = 0; i < 4; ++i) {
    int r = r0 + i * 8;
    tile[r][c] = W[(size_t)(k0 + r) * N + (n0 + c)];
  }
  __syncthreads();
#pragma unroll
  for (int i = 0; i < 4; ++i) {
    int r = r0 + i * 8;
    Wt[(size_t)(n0 + r) * K + (k0 + c)] = f2bf(tile[c][r]);
  }
}

// ---------------- LN1 + token shift + 6 mixes -> bf16 ----------------
__global__ __launch_bounds__(256) void k_ln_shift(
    const float* __restrict__ x, const float* __restrict__ w, const float* __restrict__ bias,
    const float* __restrict__ cr, const float* __restrict__ cw, const float* __restrict__ ck,
    const float* __restrict__ cv, const float* __restrict__ ca, const float* __restrict__ cg,
    u16* __restrict__ XR, u16* __restrict__ XW, u16* __restrict__ XK,
    u16* __restrict__ XV, u16* __restrict__ XA, u16* __restrict__ XG) {
  int row = blockIdx.x;
  int t = row & (Tt - 1);
  int tid = threadIdx.x;
  int col = tid * 4;
  const float* xc = x + (size_t)row * Dd + col;
  f32x4 c = *(const f32x4*)xc;
  f32x4 p = {0.f, 0.f, 0.f, 0.f};
  bool hasprev = (t != 0);
  if (hasprev) p = *(const f32x4*)(xc - Dd);
  float s1 = 0, s2 = 0, s3 = 0, s4 = 0;
#pragma unroll
  for (int j = 0; j < 4; ++j) {
    s1 += c[j]; s2 += c[j] * c[j];
    s3 += p[j]; s4 += p[j] * p[j];
  }
#pragma unroll
  for (int m = 1; m < 64; m <<= 1) {
    s1 += __shfl_xor(s1, m, 64); s2 += __shfl_xor(s2, m, 64);
    s3 += __shfl_xor(s3, m, 64); s4 += __shfl_xor(s4, m, 64);
  }
  __shared__ float red[4][4];
  int wid = tid >> 6;
  if ((tid & 63) == 0) { red[wid][0] = s1; red[wid][1] = s2; red[wid][2] = s3; red[wid][3] = s4; }
  __syncthreads();
  s1 = red[0][0] + red[1][0] + red[2][0] + red[3][0];
  s2 = red[0][1] + red[1][1] + red[2][1] + red[3][1];
  s3 = red[0][2] + red[1][2] + red[2][2] + red[3][2];
  s4 = red[0][3] + red[1][3] + red[2][3] + red[3][3];
  const float invD = 1.f / (float)Dd;
  float mc = s1 * invD, vc = s2 * invD - mc * mc;
  float rc = rsqrtf(vc + 1e-5f);
  float mp = s3 * invD, vp = s4 * invD - mp * mp;
  float rp = rsqrtf(vp + 1e-5f);
  size_t ob = (size_t)row * Dd + col;
#pragma unroll
  for (int j = 0; j < 4; ++j) {
    int cc = col + j;
    float wj = w[cc], bj = bias[cc];
    float xn = (c[j] - mc) * rc * wj + bj;
    float xp = hasprev ? ((p[j] - mp) * rp * wj + bj) : 0.f;
    float d = xp - xn;
    XR[ob + j] = f2bf(xn + d * cr[cc]);
    XW[ob + j] = f2bf(xn + d * cw[cc]);
    XK[ob + j] = f2bf(xn + d * ck[cc]);
    XV[ob + j] = f2bf(xn + d * cv[cc]);
    XA[ob + j] = f2bf(xn + d * ca[cc]);
    XG[ob + j] = f2bf(xn + d * cg[cc]);
  }
}

// ---------------- 256x256 BK=64 QKV GEMM, 512 thr, 1 barrier/iter, T2 swizzle ----------------
// Computes C = A[4096,1024] @ Bt[1024,1024]^T for ops 0..2 (f32 out).
struct GQ {
  const u16* A[3];
  const u16* Bt[3];
  float* C[3];
};

__global__ __launch_bounds__(512) void k_g256(GQ g) {
  constexpr int K = 1024;
  __shared__ __align__(16) u16 lsA[2][256 * 64];
  __shared__ __align__(16) u16 lsB[2][256 * 64];
  int d = blockIdx.x;
  int pan = d % 48, off = d / 48;       // 48%8==0 -> a panel's 4 ntiles share an XCD
  int op = pan / 16;
  int m0 = (pan % 16) * 256, n0 = off * 256;
  const u16* A = g.A[op];
  const u16* Bt = g.Bt[op];
  float* Cf = g.C[op];
  int tid = threadIdx.x;
  int w = tid >> 6, lane = tid & 63;
  int wr = w >> 2, wc = w & 3;          // wave grid 2M x 4N
  int lrow = lane & 15, lk = lane >> 4;
  int srow = tid >> 3, sseg = tid & 7;  // staging: 64 rows x 8 segs per quarter
  // swizzle constants (involution on col16 bits 4,5 keyed by row bits 2,3)
  int ssw = (sseg ^ (((srow >> 2) & 1) << 1) ^ (((srow >> 3) & 1) << 2)) * 8;
  int rsw = ((((lrow >> 2) & 1) << 1));  // lk xor mask
  int ksw = ((lrow >> 3) & 1);           // kk xor mask
  f32x4 acc[8][4];
#pragma unroll
  for (int m = 0; m < 8; ++m)
#pragma unroll
    for (int n = 0; n < 4; ++n) acc[m][n] = (f32x4){0.f, 0.f, 0.f, 0.f};

  auto stageQ = [&](int t, int p) {
    int buf = t & 1;
    int row = p * 64 + srow;
    int kt = t * 64;
    gload_lds16(A + (size_t)(m0 + row) * K + kt + ssw, &lsA[buf][row * 64 + sseg * 8]);
    gload_lds16(Bt + (size_t)(n0 + row) * K + kt + ssw, &lsB[buf][row * 64 + sseg * 8]);
  };

#pragma unroll
  for (int p = 0; p < 4; ++p) stageQ(0, p);
  __syncthreads();

  for (int t = 0; t < 16; ++t) {
    int buf = t & 1;
#pragma unroll
    for (int p = 0; p < 4; ++p) {
      if (t + 1 < 16) stageQ(t + 1, p);
      bf16x8 bfv[4][2], af[2][2];
#pragma unroll
      for (int n = 0; n < 4; ++n)
#pragma unroll
        for (int kk = 0; kk < 2; ++kk) {
          int row = wc * 64 + n * 16 + lrow;
          int col = ((kk ^ ksw) * 32) + ((lk ^ rsw) * 8);
          bfv[n][kk] = *(const bf16x8*)&lsB[buf][row * 64 + col];
        }
#pragma unroll
      for (int r = 0; r < 2; ++r)
#pragma unroll
        for (int kk = 0; kk < 2; ++kk) {
          int row = wr * 128 + (2 * p + r) * 16 + lrow;
          int col = ((kk ^ ksw) * 32) + ((lk ^ rsw) * 8);
          af[r][kk] = *(const bf16x8*)&lsA[buf][row * 64 + col];
        }
      __builtin_amdgcn_s_setprio(1);
#pragma unroll
      for (int kk = 0; kk < 2; ++kk)
#pragma unroll
        for (int r = 0; r < 2; ++r)
#pragma unroll
          for (int n = 0; n < 4; ++n)
            acc[2 * p + r][n] =
                __builtin_amdgcn_mfma_f32_16x16x32_bf16(af[r][kk], bfv[n][kk], acc[2 * p + r][n], 0, 0, 0);
      __builtin_amdgcn_s_setprio(0);
    }
    __syncthreads();  // vmcnt(0)+lgkmcnt(0) drain: next tile staged; this buf free
  }
#pragma unroll
  for (int m = 0; m < 8; ++m) {
    int rbase = m0 + wr * 128 + m * 16 + lk * 4;
#pragma unroll
    for (int n = 0; n < 4; ++n) {
      int col = n0 + wc * 64 + n * 16 + lrow;
#pragma unroll
      for (int j = 0; j < 4; ++j)
        Cf[(size_t)(rbase + j) * 1024 + col] = acc[m][n][j];
    }
  }
}

// ---------------- bf16 MFMA GEMM, BK=32 (R18 proven) ----------------
// EPI: 6=y+res->f32  7=y+bias+res->f32
template <int BM, int BN, int EPI, int GY>
__global__ __launch_bounds__(256) void k_gemm_bt(
    const u16* __restrict__ A, const u16* __restrict__ Bt,
    float* __restrict__ Cf,
    const float* __restrict__ aux, const float* __restrict__ res,
    int Ndim, int K) {
  constexpr int MR = BM / 32;
  constexpr int NR = BN / 32;
  __shared__ __align__(16) u16 lsA[BM * 32];
  __shared__ __align__(16) u16 lsB[BN * 32];
  int tid = threadIdx.x;
  int wid = tid >> 6, lane = tid & 63;
  int wr = wid >> 1, wc = wid & 1;
  int lrow = lane & 15, lk = lane >> 4;
  int d = blockIdx.x + 8 * blockIdx.y;
  int pan = d % GY, off = d / GY;
  int m0 = pan * BM, n0 = off * BN;
  f32x4 acc[MR][NR];
#pragma unroll
  for (int m = 0; m < MR; ++m)
#pragma unroll
    for (int n = 0; n < NR; ++n) acc[m][n] = (f32x4){0.f, 0.f, 0.f, 0.f};

  for (int kt = 0; kt < K; kt += 32) {
#pragma unroll
    for (int u = 0; u < BM / 64; ++u) {
      int e = u * 256 + tid;
      int row = e >> 2, kc = (e & 3) * 8;
      gload_lds16(A + (size_t)(m0 + row) * K + kt + kc, lsA + (size_t)e * 8);
    }
#pragma unroll
    for (int u = 0; u < BN / 64; ++u) {
      int e = u * 256 + tid;
      int row = e >> 2, kc = (e & 3) * 8;
      gload_lds16(Bt + (size_t)(n0 + row) * K + kt + kc, lsB + (size_t)e * 8);
    }
    __syncthreads();
    bf16x8 af[MR], bfv[NR];
#pragma unroll
    for (int m = 0; m < MR; ++m)
      af[m] = *(const bf16x8*)&lsA[(wr * (BM / 2) + m * 16 + lrow) * 32 + lk * 8];
#pragma unroll
    for (int n = 0; n < NR; ++n)
      bfv[n] = *(const bf16x8*)&lsB[(wc * (BN / 2) + n * 16 + lrow) * 32 + lk * 8];
#pragma unroll
    for (int m = 0; m < MR; ++m)
#pragma unroll
      for (int n = 0; n < NR; ++n)
        acc[m][n] = __builtin_amdgcn_mfma_f32_16x16x32_bf16(af[m], bfv[n], acc[m][n], 0, 0, 0);
    __syncthreads();
  }
#pragma unroll
  for (int m = 0; m < MR; ++m) {
    int rbase = m0 + wr * (BM / 2) + m * 16 + lk * 4;
#pragma unroll
    for (int n = 0; n < NR; ++n) {
      int col = n0 + wc * (BN / 2) + n * 16 + lrow;
#pragma unroll
      for (int j = 0; j < 4; ++j) {
        float v = acc[m][n][j];
        size_t idx = (size_t)(rbase + j) * Ndim + col;
        if constexpr (EPI == 6) { Cf[idx] = v + res[idx]; }
        else { Cf[idx] = v + aux[col] + res[idx]; }
      }
    }
  }
}

// ---------------- batched 3-GEMM (second-stage LoRA): C = A @ Bt^T, N=1024 ----------------
// epi: 0=f32  4=wlog=-0.5-log1p(exp(-(w0+y)))  5=sigmoid(a0+y)
struct G3 {
  const u16* A[3];
  const u16* Bt[3];
  float* C[3];
  const float* aux[3];
  int K[3];
  int epi[3];
};

__global__ __launch_bounds__(256) void k_gemm3(G3 g) {
  constexpr int BM = 128, BN = 128, MR = 4, NR = 4;
  int d = blockIdx.x + 8 * blockIdx.y + 256 * blockIdx.z;
  int pan = d % 96, off = d / 96;
  int z = pan / 32;
  int m0 = (pan % 32) * BM, n0 = off * BN;
  const u16* A = g.A[z];
  const u16* Bt = g.Bt[z];
  float* Cf = g.C[z];
  const float* aux = g.aux[z];
  int K = g.K[z], epi = g.epi[z];
  __shared__ __align__(16) u16 lsA[BM * 32];
  __shared__ __align__(16) u16 lsB[BN * 32];
  int tid = threadIdx.x;
  int wid = tid >> 6, lane = tid & 63;
  int wr = wid >> 1, wc = wid & 1;
  int lrow = lane & 15, lk = lane >> 4;
  f32x4 acc[MR][NR];
#pragma unroll
  for (int m = 0; m < MR; ++m)
#pragma unroll
    for (int n = 0; n < NR; ++n) acc[m][n] = (f32x4){0.f, 0.f, 0.f, 0.f};

  for (int kt = 0; kt < K; kt += 32) {
#pragma unroll
    for (int u = 0; u < 2; ++u) {
      int e = u * 256 + tid;
      int row = e >> 2, kc = (e & 3) * 8;
      gload_lds16(A + (size_t)(m0 + row) * K + kt + kc, lsA + (size_t)e * 8);
      gload_lds16(Bt + (size_t)(n0 + row) * K + kt + kc, lsB + (size_t)e * 8);
    }
    __syncthreads();
    bf16x8 af[MR], bfv[NR];
#pragma unroll
    for (int m = 0; m < MR; ++m)
      af[m] = *(const bf16x8*)&lsA[(wr * 64 + m * 16 + lrow) * 32 + lk * 8];
#pragma unroll
    for (int n = 0; n < NR; ++n)
      bfv[n] = *(const bf16x8*)&lsB[(wc * 64 + n * 16 + lrow) * 32 + lk * 8];
#pragma unroll
    for (int m = 0; m < MR; ++m)
#pragma unroll
      for (int n = 0; n < NR; ++n)
        acc[m][n] = __builtin_amdgcn_mfma_f32_16x16x32_bf16(af[m], bfv[n], acc[m][n], 0, 0, 0);
    __syncthreads();
  }
#pragma unroll
  for (int m = 0; m < MR; ++m) {
    int rbase = m0 + wr * 64 + m * 16 + lk * 4;
#pragma unroll
    for (int n = 0; n < NR; ++n) {
      int col = n0 + wc * 64 + n * 16 + lrow;
#pragma unroll
      for (int j = 0; j < 4; ++j) {
        float v = acc[m][n][j];
        size_t idx = (size_t)(rbase + j) * 1024 + col;
        if (epi == 0) Cf[idx] = v;
        else if (epi == 4) Cf[idx] = -0.5f - logf(1.f + __expf(-(aux[col] + v)));
        else Cf[idx] = 1.f / (1.f + __expf(-(aux[col] + v)));
      }
    }
  }
}

// ---------------- fused first-stage LoRA GEMMs (R18 proven) ----------------
__global__ __launch_bounds__(256) void k_lora1(
    const u16* __restrict__ XW, const u16* __restrict__ XA, const u16* __restrict__ XG,
    const u16* __restrict__ W1t, const u16* __restrict__ A1t, const u16* __restrict__ G1t,
    u16* __restrict__ HW, u16* __restrict__ HA, u16* __restrict__ HG) {
  constexpr int BM = 128, BN = 64, NR = 2, MR = 4, K = 1024;
  int z = blockIdx.z;
  int Ndim = (z == 2) ? 128 : 64;
  int n0 = blockIdx.x * BN;
  if (n0 >= Ndim) return;
  const u16* A = (z == 0) ? XW : (z == 1) ? XA : XG;
  const u16* Bt = (z == 0) ? W1t : (z == 1) ? A1t : G1t;
  u16* Cb = (z == 0) ? HW : (z == 1) ? HA : HG;
  __shared__ __align__(16) u16 lsA[BM * 32];
  __shared__ __align__(16) u16 lsB[BN * 32];
  int tid = threadIdx.x;
  int wid = tid >> 6, lane = tid & 63;
  int wr = wid >> 1, wc = wid & 1;
  int lrow = lane & 15, lk = lane >> 4;
  int m0 = blockIdx.y * BM;
  f32x4 acc[MR][NR];
#pragma unroll
  for (int m = 0; m < MR; ++m)
#pragma unroll
    for (int n = 0; n < NR; ++n) acc[m][n] = (f32x4){0.f, 0.f, 0.f, 0.f};
  for (int kt = 0; kt < K; kt += 32) {
#pragma unroll
    for (int u = 0; u < BM / 64; ++u) {
      int e = u * 256 + tid;
      int row = e >> 2, kc = (e & 3) * 8;
      gload_lds16(A + (size_t)(m0 + row) * K + kt + kc, lsA + (size_t)(u * 256 + wid * 64) * 8);
    }
    {
      int row = tid >> 2, kc = (tid & 3) * 8;
      gload_lds16(Bt + (size_t)(n0 + row) * K + kt + kc, lsB + (size_t)(wid * 64) * 8);
    }
    __syncthreads();
    bf16x8 af[MR], bfv[NR];
#pragma unroll
    for (int m = 0; m < MR; ++m)
      af[m] = *(const bf16x8*)&lsA[(wr * 64 + m * 16 + lrow) * 32 + lk * 8];
#pragma unroll
    for (int n = 0; n < NR; ++n)
      bfv[n] = *(const bf16x8*)&lsB[(wc * 32 + n * 16 + lrow) * 32 + lk * 8];
#pragma unroll
    for (int m = 0; m < MR; ++m)
#pragma unroll
      for (int n = 0; n < NR; ++n)
        acc[m][n] = __builtin_amdgcn_mfma_f32_16x16x32_bf16(af[m], bfv[n], acc[m][n], 0, 0, 0);
    __syncthreads();
  }
#pragma unroll
  for (int m = 0; m < MR; ++m) {
    int rbase = m0 + wr * 64 + m * 16 + lk * 4;
#pragma unroll
    for (int n = 0; n < NR; ++n) {
      int col = n0 + wc * 32 + n * 16 + lrow;
#pragma unroll
      for (int j = 0; j < 4; ++j) {
        float v = acc[m][n][j];
        float r = (z == 0) ? tanhf(v) : (z == 1) ? v : 1.f / (1.f + __expf(-v));
        Cb[(size_t)(rbase + j) * Ndim + col] = f2bf(r);
      }
    }
  }
}

// ================= chunked delta-rule scan (prep fused, parallel cumsum) =================
// TS packed tile (u16 units): M1[16][64] @0, M2 @1024, G1[16][32] @2048, G2[64][32] @2560, TOT 4608
static constexpr int TS_M1 = 0, TS_M2 = 1024, TS_G1 = 2048, TS_G2 = 2560, TS_TOT = 4608;

__global__ __launch_bounds__(256) void k_chunk(
    const float* __restrict__ WLOG, const float* __restrict__ KRAW,
    const float* __restrict__ Af, const float* __restrict__ kk_c,
    const float* __restrict__ ka_c,
    const float* __restrict__ R, const float* __restrict__ V,
    u16* __restrict__ TSg, u16* __restrict__ Opg, u16* __restrict__ Udg,
    float* __restrict__ ECg) {
  __shared__ __align__(16) float ela[17][64];
  __shared__ __align__(16) float e8r[64];
  __shared__ __align__(16) u16 Fkkb[16][72];
  __shared__ __align__(16) u16 Frb[16][72];
  __shared__ __align__(16) u16 Gab[16][72];
  __shared__ __align__(16) u16 Gk2b[16][72];
  __shared__ __align__(16) u16 pb[336][40];
  float* lwf = (float*)&pb[272][0];
  float* mf = (float*)&pb[272][0];
  float* gsum = (float*)&Fkkb[0][0];
  int bx = blockIdx.x;
  int c = bx & 63, bh = bx >> 6;
  int b = bh >> 4, h = bh & 15;
  int tid = threadIdx.x;
  int lane = tid & 63, w = tid >> 6;
  int lr = lane & 15, lq = lane >> 4;
  size_t tau = (size_t)bx;
  size_t rowbase = (size_t)(b * 1024 + c * 16) * 1024 + h * 64;

  for (int i = tid; i < 272 * 16; i += 256)
    ((u32*)pb)[(i >> 4) * 20 + (i & 15)] = 0u;
  // P1a parallel cumsum
  {
    int k = tid & 63, q = tid >> 6;
    const float* wp = WLOG + rowbase + k;
    float w0v = wp[(size_t)(4 * q + 0) * 1024];
    float w1v = wp[(size_t)(4 * q + 1) * 1024];
    float w2v = wp[(size_t)(4 * q + 2) * 1024];
    float w3v = wp[(size_t)(4 * q + 3) * 1024];
    float p0 = w0v, p1 = p0 + w1v, p2 = p1 + w2v, p3 = p2 + w3v;
    gsum[q * 64 + k] = p3;
    __syncthreads();
    float base = 0.f;
#pragma unroll
    for (int qq = 0; qq < 3; ++qq)
      if (qq < q) base += gsum[qq * 64 + k];
    if (q == 0) lwf[0 * 64 + k] = 0.f;
    lwf[(4 * q + 1) * 64 + k] = base + p0;
    lwf[(4 * q + 2) * 64 + k] = base + p1;
    lwf[(4 * q + 3) * 64 + k] = base + p2;
    lwf[(4 * q + 4) * 64 + k] = base + p3;
  }
  __syncthreads();
  for (int i = tid; i < 17 * 64; i += 256) {
    int t = i >> 6, k = i & 63;
    ela[t][k] = expf(lwf[t * 64 + k] - lwf[8 * 64 + k]);
  }
  if (tid < 64) e8r[tid] = expf(lwf[8 * 64 + tid]);
  __syncthreads();
  // P2 fused prep (kk normalize) + operand builds + M1/M2/EC
  {
    int tt = tid >> 4, k0 = (tid & 15) * 4;
    size_t grow = rowbase + (size_t)tt * 1024 + k0;
    f32x4 kr = *(const f32x4*)(KRAW + grow);
    f32x4 av = *(const f32x4*)(Af + grow);
    f32x4 rv = *(const f32x4*)(R + grow);
    f32x4 kkc = *(const f32x4*)(kk_c + ((h * 64) + k0));
    f32x4 kac = *(const f32x4*)(ka_c + ((h * 64) + k0));
    f32x4 kk0 = kr * kkc;
    float ss = kk0[0] * kk0[0] + kk0[1] * kk0[1] + kk0[2] * kk0[2] + kk0[3] * kk0[3];
    ss += __shfl_xor(ss, 1, 64);
    ss += __shfl_xor(ss, 2, 64);
    ss += __shfl_xor(ss, 4, 64);
    ss += __shfl_xor(ss, 8, 64);
    float inv = 1.f / fmaxf(sqrtf(ss), 1e-12f);
    f32x4 ea = *(const f32x4*)&ela[tt][k0];
    f32x4 ea1 = *(const f32x4*)&ela[tt + 1][k0];
    f32x4 e84 = *(const f32x4*)&e8r[k0];
    u16 m1p[4], m2p[4], fk[4], fr[4], ga[4], gk[4];
#pragma unroll
    for (int j = 0; j < 4; ++j) {
      float kkv = kk0[j] * inv;
      float kkav = kkv * av[j];
      float kpv = kr[j] * (1.f + (av[j] - 1.f) * kac[j]);
      float fkk = kkv * ea[j];
      float frv = rv[j] * ea1[j];
      float eb1 = __builtin_amdgcn_rcpf(ea1[j]);
      fk[j] = f2bf(fkk);
      fr[j] = f2bf(frv);
      m1p[j] = f2bf(fkk * e84[j]);
      m2p[j] = f2bf(frv * e84[j]);
      ga[j] = f2bf(kkav * eb1);
      gk[j] = f2bf(kpv * eb1);
    }
    *(u32x2*)&Fkkb[tt][k0] = *(u32x2*)fk;
    *(u32x2*)&Frb[tt][k0] = *(u32x2*)fr;
    *(u32x2*)&Gab[tt][k0] = *(u32x2*)ga;
    *(u32x2*)&Gk2b[tt][k0] = *(u32x2*)gk;
    *(u32x2*)(TSg + tau * TS_TOT + TS_M1 + tt * 64 + k0) = *(u32x2*)m1p;
    *(u32x2*)(TSg + tau * TS_TOT + TS_M2 + tt * 64 + k0) = *(u32x2*)m2p;
    if (tid < 64) {
      f32x4 ec;
#pragma unroll
      for (int kt = 0; kt < 4; ++kt) {
        int kk2 = kt * 16 + (tid & 15);
        ec[kt] = ela[16][kk2] * e8r[kk2];
      }
      *(f32x4*)(ECg + tau * 256 + tid * 4) = ec;
    }
  }
  __syncthreads();
  // P3a k-major transposed builds (swizzled) — V direct from global
  {
    int k = tid & 63, tq = tid >> 6;
    float e16 = ela[16][k];
    u16 vt4[4], ad4[4], kd4[4];
#pragma unroll
    for (int i = 0; i < 4; ++i) {
      int tt = tq * 4 + i;
      float vv = V[rowbase + (size_t)tt * 1024 + k];
      vt4[i] = f2bf(vv);
      ad4[i] = f2bf(bf2f(Gab[tt][k]) * e16);
      kd4[i] = f2bf(bf2f(Gk2b[tt][k]) * e16);
    }
    int half = (tq & 1) * 4, unit = tq >> 1;
    *(u32x2*)&pb[k][(unit ^ ((k >> 3) & 3)) * 8 + half] = *(u32x2*)vt4;
    *(u32x2*)&pb[144 + k][(unit ^ (((144 + k) >> 3) & 3)) * 8 + half] = *(u32x2*)ad4;
    *(u32x2*)&pb[208 + k][(unit ^ (((208 + k) >> 3) & 3)) * 8 + half] = *(u32x2*)kd4;
  }
  // P3b C x C matrices via MFMA; wave w -> mat w (into mf overlay)
  {
    const u16* Ab = (w < 2) ? &Fkkb[0][0] : &Frb[0][0];
    const u16* Bb = (w & 1) ? &Gk2b[0][0] : &Gab[0][0];
    f32x4 d = {0.f, 0.f, 0.f, 0.f};
    bf16x8 a0 = *(const bf16x8*)(Ab + lr * 72 + lq * 8);
    bf16x8 a1 = *(const bf16x8*)(Ab + lr * 72 + 32 + lq * 8);
    bf16x8 b0 = *(const bf16x8*)(Bb + lr * 72 + lq * 8);
    bf16x8 b1 = *(const bf16x8*)(Bb + lr * 72 + 32 + lq * 8);
    d = __builtin_amdgcn_mfma_f32_16x16x32_bf16(a0, b0, d, 0, 0, 0);
    d = __builtin_amdgcn_mfma_f32_16x16x32_bf16(a1, b1, d, 0, 0, 0);
    bool strict = (w < 2);
#pragma unroll
    for (int j = 0; j < 4; ++j) {
      int rowt = lq * 4 + j, coli = lr;
      bool keep = strict ? (coli < rowt) : (coli <= rowt);
      mf[(w * 16 + rowt) * 17 + coli] = keep ? d[j] : 0.f;
    }
  }
  __syncthreads();
  // P4 Tinv solve (wave 0) || P4.5 f32->bf16 mat copies (waves 1-3)
  if (tid < 64) {
    float x[16];
#pragma unroll
    for (int i = 0; i < 16; ++i) x[i] = (i == lane) ? 1.f : 0.f;
#pragma unroll
    for (int i = 14; i >= 0; --i) {
      float s = 0.f;
#pragma unroll
      for (int m = i + 1; m < 16; ++m) s += mf[m * 17 + i] * x[m];
      x[i] -= s;
    }
    if (lane < 16) {
#pragma unroll
      for (int i = 0; i < 16; ++i) {
        u16 v = f2bf(x[i]);
        pb[112 + i][lane] = v;
        pb[128 + lane][i] = v;
      }
    }
  } else {
    int id = tid - 64;
    for (int i = id; i < 768; i += 192) {
      int m = i >> 8, rem = i & 255, r = rem >> 4, cc = rem & 15;
      pb[64 + m * 16 + r][cc] = f2bf(mf[((1 + m) * 16 + r) * 17 + cc]);
    }
  }
  __syncthreads();
  // P5a: T1n = -(V @ Kkk^T)
  {
    int rv2 = 16 * w + lr;
    bf16x8 a = *(const bf16x8*)&pb[rv2][swz8(rv2, lq)];
    bf16x8 bb = *(const bf16x8*)&pb[64 + lr][lq * 8];
    f32x4 d = {0.f, 0.f, 0.f, 0.f};
    d = __builtin_amdgcn_mfma_f32_16x16x32_bf16(a, bb, d, 0, 0, 0);
#pragma unroll
    for (int j = 0; j < 4; ++j) {
      int rw = 272 + 16 * w + lq * 4 + j;
      pb[rw][lr] = f2bf(-d[j]);
      pb[rw][16 + lr] = 0;
    }
  }
  // P5b: Xp = T1n @ Tinv
  {
    bf16x8 a = *(const bf16x8*)&pb[272 + 16 * w + lr][lq * 8];
    bf16x8 bb = *(const bf16x8*)&pb[128 + lr][lq * 8];
    f32x4 d = {0.f, 0.f, 0.f, 0.f};
    d = __builtin_amdgcn_mfma_f32_16x16x32_bf16(a, bb, d, 0, 0, 0);
#pragma unroll
    for (int j = 0; j < 4; ++j) pb[272 + 16 * w + lq * 4 + j][lr] = f2bf(d[j]);
  }
  // P5c/P6/P7: G1 (wave0), G2 ntile w, Op mtile w, Ud mtile w
  {
    bf16x8 atv = *(const bf16x8*)&pb[112 + lr][lq * 8];
    if (w == 0) {
      bf16x8 bb = *(const bf16x8*)&pb[80 + lr][lq * 8];
      f32x4 d = {0.f, 0.f, 0.f, 0.f};
      d = __builtin_amdgcn_mfma_f32_16x16x32_bf16(atv, bb, d, 0, 0, 0);
      u16* g1g = TSg + tau * TS_TOT + TS_G1;
#pragma unroll
      for (int j = 0; j < 4; ++j) g1g[lr * 32 + lq * 4 + j] = f2bf(d[j]);
      *(u32x2*)(g1g + lr * 32 + 16 + lq * 4) = (u32x2){0u, 0u};
    }
    {
      int ra = 144 + 16 * w + lr;
      bf16x8 bb = *(const bf16x8*)&pb[ra][swz8(ra, lq)];
      f32x4 d = {0.f, 0.f, 0.f, 0.f};
      d = __builtin_amdgcn_mfma_f32_16x16x32_bf16(atv, bb, d, 0, 0, 0);
      u16* g2g = TSg + tau * TS_TOT + TS_G2;
#pragma unroll
      for (int j = 0; j < 4; ++j) g2g[(16 * w + lr) * 32 + lq * 4 + j] = f2bf(d[j]);
      *(u32x2*)(g2g + (16 * w + lr) * 32 + 16 + lq * 4) = (u32x2){0u, 0u};
    }
    int rv2 = 16 * w + lr;
    bf16x8 axp = *(const bf16x8*)&pb[272 + 16 * w + lr][lq * 8];
    bf16x8 avt = *(const bf16x8*)&pb[rv2][swz8(rv2, lq)];
    {
      bf16x8 bar = *(const bf16x8*)&pb[80 + lr][lq * 8];
      bf16x8 bkr = *(const bf16x8*)&pb[96 + lr][lq * 8];
      f32x4 d = {0.f, 0.f, 0.f, 0.f};
      d = __builtin_amdgcn_mfma_f32_16x16x32_bf16(axp, bar, d, 0, 0, 0);
      d = __builtin_amdgcn_mfma_f32_16x16x32_bf16(avt, bkr, d, 0, 0, 0);
      u16 o4[4];
#pragma unroll
      for (int j = 0; j < 4; ++j) o4[j] = f2bf(d[j]);
      *(u32x2*)(Opg + (tau * 256 + w * 64 + lane) * 4) = *(u32x2*)o4;
    }
#pragma unroll
    for (int nt = 0; nt < 4; ++nt) {
      int ra = 144 + 16 * nt + lr, rk2 = 208 + 16 * nt + lr;
      bf16x8 bad = *(const bf16x8*)&pb[ra][swz8(ra, lq)];
      bf16x8 bkd = *(const bf16x8*)&pb[rk2][swz8(rk2, lq)];
      f32x4 d = {0.f, 0.f, 0.f, 0.f};
      d = __builtin_amdgcn_mfma_f32_16x16x32_bf16(axp, bad, d, 0, 0, 0);
      d = __builtin_amdgcn_mfma_f32_16x16x32_bf16(avt, bkd, d, 0, 0, 0);
      u16 u4[4];
#pragma unroll
      for (int j = 0; j < 4; ++j) u4[j] = f2bf(d[j]);
      *(u32x2*)(Udg + (tau * 256 + w * 64 + lane) * 16 + nt * 4) = *(u32x2*)u4;
    }
  }
}

// ---------------- sequential chunk scan: 256 wgs x 1 wave ----------------
struct Frags {
  bf16x8 m10, m11, m20, m21, g1b, g2b0, g2b1, g2b2, g2b3;
  u32x4 ud0, ud1;
  u32x2 opu;
  f32x4 ef;
};

__global__ __launch_bounds__(64) void k_scan2(
    const u16* __restrict__ TSg, const u16* __restrict__ Opg,
    const u16* __restrict__ Udg, const float* __restrict__ ECg,
    float* __restrict__ O) {
  __shared__ __align__(16) u16 Sb[16][72];
  __shared__ __align__(16) u16 negb[16][40];
  int bx = blockIdx.x;
  int sw = (bx & 7) * 32 + (bx >> 3);
  int bh = sw >> 2, vs = sw & 3;
  int b = bh >> 4, h = bh & 15;
  int l = threadIdx.x;
  int lr = l & 15, lq = l >> 4;
  if (l < 16) {
    *(u32x4*)&negb[l][16] = (u32x4){0u, 0u, 0u, 0u};
    *(u32x4*)&negb[l][24] = (u32x4){0u, 0u, 0u, 0u};
  }
  f32x4 S[4];
#pragma unroll
  for (int kt = 0; kt < 4; ++kt) S[kt] = (f32x4){0.f, 0.f, 0.f, 0.f};

  auto loadF = [&](int cc) {
    Frags f;
    size_t tau = (size_t)(bh * 64 + cc);
    const u16* ts = TSg + tau * TS_TOT;
    f.m10 = *(const bf16x8*)(ts + TS_M1 + lr * 64 + lq * 8);
    f.m11 = *(const bf16x8*)(ts + TS_M1 + lr * 64 + 32 + lq * 8);
    f.m20 = *(const bf16x8*)(ts + TS_M2 + lr * 64 + lq * 8);
    f.m21 = *(const bf16x8*)(ts + TS_M2 + lr * 64 + 32 + lq * 8);
    f.g1b = *(const bf16x8*)(ts + TS_G1 + lr * 32 + lq * 8);
    f.g2b0 = *(const bf16x8*)(ts + TS_G2 + (0 * 16 + lr) * 32 + lq * 8);
    f.g2b1 = *(const bf16x8*)(ts + TS_G2 + (1 * 16 + lr) * 32 + lq * 8);
    f.g2b2 = *(const bf16x8*)(ts + TS_G2 + (2 * 16 + lr) * 32 + lq * 8);
    f.g2b3 = *(const bf16x8*)(ts + TS_G2 + (3 * 16 + lr) * 32 + lq * 8);
    f.ud0 = *(const u32x4*)(Udg + (tau * 256 + vs * 64 + l) * 16);
    f.ud1 = *(const u32x4*)(Udg + (tau * 256 + vs * 64 + l) * 16 + 8);
    f.opu = *(const u32x2*)(Opg + (tau * 256 + vs * 64 + l) * 4);
    f.ef = *(const f32x4*)(ECg + tau * 256 + l * 4);
    return f;
  };

  auto doChunk = [&](int c, const Frags& f) {
#pragma unroll
    for (int kt = 0; kt < 4; ++kt)
#pragma unroll
      for (int j = 0; j < 4; ++j) Sb[lq * 4 + j][kt * 16 + lr] = f2bf(S[kt][j]);
    bf16x8 a0 = *(const bf16x8*)&Sb[lr][lq * 8];
    bf16x8 a1 = *(const bf16x8*)&Sb[lr][32 + lq * 8];
    f32x4 s0b = {0.f, 0.f, 0.f, 0.f}, s0r = {0.f, 0.f, 0.f, 0.f};
    s0b = __builtin_amdgcn_mfma_f32_16x16x32_bf16(a0, f.m10, s0b, 0, 0, 0);
    s0b = __builtin_amdgcn_mfma_f32_16x16x32_bf16(a1, f.m11, s0b, 0, 0, 0);
    s0r = __builtin_amdgcn_mfma_f32_16x16x32_bf16(a0, f.m20, s0r, 0, 0, 0);
    s0r = __builtin_amdgcn_mfma_f32_16x16x32_bf16(a1, f.m21, s0r, 0, 0, 0);
#pragma unroll
    for (int j = 0; j < 4; ++j) negb[lq * 4 + j][lr] = f2bf(-s0b[j]);
    bf16x8 nb0 = *(const bf16x8*)&negb[lr][lq * 8];
    f32x4 o = __builtin_amdgcn_mfma_f32_16x16x32_bf16(nb0, f.g1b, s0r, 0, 0, 0);
    u16 op4[4];
    *(u32x2*)op4 = f.opu;
#pragma unroll
    for (int j = 0; j < 4; ++j) o[j] += bf2f(op4[j]);
    size_t orow = ((size_t)b * 1024 + c * 16 + lr) * 1024 + h * 64 + vs * 16 + lq * 4;
    *(f32x4*)(O + orow) = o;
    u16 udh[16];
    *(u32x4*)&udh[0] = f.ud0;
    *(u32x4*)&udh[8] = f.ud1;
    f32x4 cin0, cin1, cin2, cin3;
#pragma unroll
    for (int j = 0; j < 4; ++j) {
      cin0[j] = S[0][j] * f.ef[0] + bf2f(udh[0 * 4 + j]);
      cin1[j] = S[1][j] * f.ef[1] + bf2f(udh[1 * 4 + j]);
      cin2[j] = S[2][j] * f.ef[2] + bf2f(udh[2 * 4 + j]);
      cin3[j] = S[3][j] * f.ef[3] + bf2f(udh[3 * 4 + j]);
    }
    S[0] = __builtin_amdgcn_mfma_f32_16x16x32_bf16(nb0, f.g2b0, cin0, 0, 0, 0);
    S[1] = __builtin_amdgcn_mfma_f32_16x16x32_bf16(nb0, f.g2b1, cin1, 0, 0, 0);
    S[2] = __builtin_amdgcn_mfma_f32_16x16x32_bf16(nb0, f.g2b2, cin2, 0, 0, 0);
    S[3] = __builtin_amdgcn_mfma_f32_16x16x32_bf16(nb0, f.g2b3, cin3, 0, 0, 0);
  };

  Frags fA = loadF(0);
  Frags fB = loadF(1);
  for (int cp = 0; cp < 62; cp += 2) {
    doChunk(cp, fA);
    fA = loadF(cp + 2);
    doChunk(cp + 1, fB);
    fB = loadF(cp + 3);
  }
  doChunk(62, fA);
  doChunk(63, fB);
}

// ---------------- per-head groupnorm + bonus + gate -> bf16 (kp inline) ----------------
__global__ __launch_bounds__(256) void k_gn_gate(
    const float* __restrict__ O, const float* __restrict__ R,
    const float* __restrict__ KRAW, const float* __restrict__ Af,
    const float* __restrict__ ka_c,
    const float* __restrict__ V, const float* __restrict__ G,
    const float* __restrict__ r_k, const float* __restrict__ gn_w, const float* __restrict__ gn_b,
    u16* __restrict__ GT) {
  int row = blockIdx.x;
  int tid = threadIdx.x;
  int col = tid * 4;
  size_t idx = (size_t)row * Dd + col;
  f32x4 o = *(const f32x4*)(O + idx), r = *(const f32x4*)(R + idx),
        kr = *(const f32x4*)(KRAW + idx), av = *(const f32x4*)(Af + idx),
        v = *(const f32x4*)(V + idx), g = *(const f32x4*)(G + idx);
  f32x4 kac = *(const f32x4*)(ka_c + col);
  f32x4 rk = *(const f32x4*)(r_k + col), gw = *(const f32x4*)(gn_w + col),
        gb = *(const f32x4*)(gn_b + col);
  float so = 0, so2 = 0, sb = 0;
#pragma unroll
  for (int j = 0; j < 4; ++j) {
    float kp = kr[j] * (1.f + (av[j] - 1.f) * kac[j]);
    so += o[j]; so2 += o[j] * o[j]; sb += r[j] * kp * rk[j];
  }
#pragma unroll
  for (int m = 1; m < 16; m <<= 1) {
    so += __shfl_xor(so, m, 64);
    so2 += __shfl_xor(so2, m, 64);
    sb += __shfl_xor(sb, m, 64);
  }
  float mu = so * (1.f / 64.f);
  float var = so2 * (1.f / 64.f) - mu * mu;
  float rs = rsqrtf(var + 64e-5f);
#pragma unroll
  for (int j = 0; j < 4; ++j) {
    float on = (o[j] - mu) * rs * gw[j] + gb[j] + sb * v[j];
    GT[idx + j] = f2bf(on * g[j]);
  }
}

// ---------------- plain LN -> bf16 ----------------
__global__ __launch_bounds__(256) void k_ln(
    const float* __restrict__ X, const float* __restrict__ w, const float* __restrict__ bias,
    u16* __restrict__ OUT) {
  int row = blockIdx.x;
  int tid = threadIdx.x;
  int col = tid * 4;
  size_t idx = (size_t)row * Dd + col;
  f32x4 c = *(const f32x4*)(X + idx);
  float s1 = 0, s2 = 0;
#pragma unroll
  for (int j = 0; j < 4; ++j) { s1 += c[j]; s2 += c[j] * c[j]; }
#pragma unroll
  for (int m = 1; m < 64; m <<= 1) { s1 += __shfl_xor(s1, m, 64); s2 += __shfl_xor(s2, m, 64); }
  __shared__ float red[4][2];
  int wid = tid >> 6;
  if ((tid & 63) == 0) { red[wid][0] = s1; red[wid][1] = s2; }
  __syncthreads();
  s1 = red[0][0] + red[1][0] + red[2][0] + red[3][0];
  s2 = red[0][1] + red[1][1] + red[2][1] + red[3][1];
  const float invD = 1.f / (float)Dd;
  float mc = s1 * invD;
  float rc = rsqrtf(s2 * invD - mc * mc + 1e-5f);
#pragma unroll
  for (int j = 0; j < 4; ++j)
    OUT[idx + j] = f2bf((c[j] - mc) * rc * w[col + j] + bias[col + j]);
}

extern "C" void kernel_launch(void* const* d_in, const int* in_sizes, int n_in,
                              void* d_out, int out_size, void* d_ws, size_t ws_size,
                              hipStream_t stream) {
  const float* x    = (const float*)d_in[0];
  const float* ln1w = (const float*)d_in[1];
  const float* ln1b = (const float*)d_in[2];
  const float* ln2w = (const float*)d_in[3];
  const float* ln2b = (const float*)d_in[4];
  const float* xr_c = (const float*)d_in[5];
  const float* xw_c = (const float*)d_in[6];
  const float* xk_c = (const float*)d_in[7];
  const float* xv_c = (const float*)d_in[8];
  const float* xa_c = (const float*)d_in[9];
  const float* xg_c = (const float*)d_in[10];
  const float* Wr   = (const float*)d_in[11];
  const float* Wk   = (const float*)d_in[12];
  const float* Wv   = (const float*)d_in[13];
  const float* w0   = (const float*)d_in[14];
  const float* w1   = (const float*)d_in[15];
  const float* w2   = (const float*)d_in[16];
  const float* a0   = (const float*)d_in[17];
  const float* a1   = (const float*)d_in[18];
  const float* a2   = (const float*)d_in[19];
  const float* g1   = (const float*)d_in[20];
  const float* g2   = (const float*)d_in[21];
  const float* k_k  = (const float*)d_in[22];
  const float* k_a  = (const float*)d_in[23];
  const float* r_k  = (const float*)d_in[24];
  const float* gnw  = (const float*)d_in[25];
  const float* gnb  = (const float*)d_in[26];
  const float* Wo   = (const float*)d_in[27];
  const float* mlpw = (const float*)d_in[28];
  const float* mlpb = (const float*)d_in[29];

  char* ws = (char*)d_ws;
  const size_t MBy = 1024 * 1024;
  u16* WT_R  = (u16*)(ws + 0 * MBy);
  u16* WT_K  = (u16*)(ws + 2 * MBy);
  u16* WT_V  = (u16*)(ws + 4 * MBy);
  u16* WT_O  = (u16*)(ws + 6 * MBy);
  u16* WT_M  = (u16*)(ws + 8 * MBy);
  u16* WT_w1 = (u16*)(ws + 10 * MBy);
  u16* WT_a1 = (u16*)(ws + 10 * MBy + 128 * 1024);
  u16* WT_g1 = (u16*)(ws + 10 * MBy + 256 * 1024);
  u16* WT_w2 = (u16*)(ws + 10 * MBy + 512 * 1024);
  u16* WT_a2 = (u16*)(ws + 10 * MBy + 640 * 1024);
  u16* WT_g2 = (u16*)(ws + 10 * MBy + 768 * 1024);
  u16* XR = (u16*)(ws + 12 * MBy);
  u16* XW = (u16*)(ws + 20 * MBy);
  u16* XK = (u16*)(ws + 28 * MBy);
  u16* XV = (u16*)(ws + 36 * MBy);
  u16* XA = (u16*)(ws + 44 * MBy);
  u16* XG = (u16*)(ws + 52 * MBy);
  float* Rf    = (float*)(ws + 60 * MBy);
  float* KRAW  = (float*)(ws + 76 * MBy);
  float* WLOGf = (float*)(ws + 92 * MBy);
  float* Af    = (float*)(ws + 108 * MBy);
  float* Gf    = (float*)(ws + 124 * MBy);
  u16* HW = (u16*)(ws + 140 * MBy);
  u16* HA = (u16*)(ws + 140 * MBy + 512 * 1024);
  u16* HG = (u16*)(ws + 141 * MBy);
  // overlays
  float* Of   = (float*)(ws + 12 * MBy);   // over XR+XW (dead after QKV/lora1)
  float* X1   = (float*)(ws + 28 * MBy);   // over XK+XV (dead after QKV)
  u16* GT  = (u16*)(ws + 92 * MBy);        // over WLOGf (dead after k_chunk)
  u16* XN2 = (u16*)(ws + 116 * MBy);       // over Af upper half (dead after gn_gate)
  // chunked-scan tile arrays
  u16* TSg   = (u16*)(ws + 144 * MBy);
  u16* Udg   = (u16*)(ws + 188 * MBy);
  u16* Opg   = (u16*)(ws + 220 * MBy);
  float* ECg = (float*)(ws + 228 * MBy);
  float* OUT_X = (float*)d_out;
  float* OUT_V = (float*)d_out + (size_t)Mrows * Dd;

  dim3 blk(256);
  TransDesc td;
  td.src[0] = Wr;   td.dst[0] = WT_R;  td.K[0] = 1024; td.N[0] = 1024;
  td.src[1] = Wk;   td.dst[1] = WT_K;  td.K[1] = 1024; td.N[1] = 1024;
  td.src[2] = Wv;   td.dst[2] = WT_V;  td.K[2] = 1024; td.N[2] = 1024;
  td.src[3] = Wo;   td.dst[3] = WT_O;  td.K[3] = 1024; td.N[3] = 1024;
  td.src[4] = mlpw; td.dst[4] = WT_M;  td.K[4] = 1024; td.N[4] = 1024;
  td.src[5] = w1;   td.dst[5] = WT_w1; td.K[5] = 1024; td.N[5] = 64;
  td.src[6] = a1;   td.dst[6] = WT_a1; td.K[6] = 1024; td.N[6] = 64;
  td.src[7] = g1;   td.dst[7] = WT_g1; td.K[7] = 1024; td.N[7] = 128;
  td.src[8] = w2;   td.dst[8] = WT_w2; td.K[8] = 64;   td.N[8] = 1024;
  td.src[9] = a2;   td.dst[9] = WT_a2; td.K[9] = 64;   td.N[9] = 1024;
  td.src[10] = g2;  td.dst[10] = WT_g2; td.K[10] = 128; td.N[10] = 1024;
  k_transpose_all<<<dim3(32, 32, 11), blk, 0, stream>>>(td);

  k_ln_shift<<<Mrows, blk, 0, stream>>>(x, ln1w, ln1b, xr_c, xw_c, xk_c, xv_c, xa_c, xg_c,
                                        XR, XW, XK, XV, XA, XG);

  k_lora1<<<dim3(2, 32, 3), blk, 0, stream>>>(XW, XA, XG, WT_w1, WT_a1, WT_g1, HW, HA, HG);

  GQ gq;
  gq.A[0] = XR; gq.Bt[0] = WT_R; gq.C[0] = Rf;
  gq.A[1] = XK; gq.Bt[1] = WT_K; gq.C[1] = KRAW;
  gq.A[2] = XV; gq.Bt[2] = WT_V; gq.C[2] = OUT_V;
  k_g256<<<dim3(192), dim3(512), 0, stream>>>(gq);

  G3 gw;
  gw.A[0] = HW; gw.Bt[0] = WT_w2; gw.C[0] = WLOGf; gw.aux[0] = w0;      gw.K[0] = 64;  gw.epi[0] = 4;
  gw.A[1] = HA; gw.Bt[1] = WT_a2; gw.C[1] = Af;    gw.aux[1] = a0;      gw.K[1] = 64;  gw.epi[1] = 5;
  gw.A[2] = HG; gw.Bt[2] = WT_g2; gw.C[2] = Gf;    gw.aux[2] = nullptr; gw.K[2] = 128; gw.epi[2] = 0;
  k_gemm3<<<dim3(8, 32, 3), blk, 0, stream>>>(gw);

  k_chunk<<<4096, blk, 0, stream>>>(WLOGf, KRAW, Af, k_k, k_a, Rf, OUT_V, TSg, Opg, Udg, ECg);
  k_scan2<<<256, dim3(64), 0, stream>>>(TSg, Opg, Udg, ECg, Of);
  k_gn_gate<<<Mrows, blk, 0, stream>>>(Of, Rf, KRAW, Af, k_a, OUT_V, Gf, r_k, gnw, gnb, GT);
  k_gemm_bt<64, 128, 6, 64><<<dim3(8, 64), blk, 0, stream>>>(GT, WT_O, X1, nullptr, x, 1024, 1024);
  k_ln<<<Mrows, blk, 0, stream>>>(X1, ln2w, ln2b, XN2);
  k_gemm_bt<64, 128, 7, 64><<<dim3(8, 64), blk, 0, stream>>>(XN2, WT_M, OUT_X, mlpb, X1, 1024, 1024);
}

// Round 22
// 283.349 us; speedup vs baseline: 1.1134x; 1.1134x over previous
//
#include <hip/hip_runtime.h>
#include <hip/hip_bf16.h>
#include <cstdint>

typedef unsigned short u16;
typedef unsigned int u32;
typedef __attribute__((__ext_vector_type__(4))) float f32x4;
typedef __attribute__((__ext_vector_type__(4))) u32 u32x4;
typedef __attribute__((__ext_vector_type__(2))) u32 u32x2;
typedef __attribute__((__ext_vector_type__(8))) __bf16 bf16x8;

#define DEV __device__ __forceinline__

static constexpr int Tt = 1024, Dd = 1024;
static constexpr int Mrows = 4096;  // B*T

DEV u16 f2bf(float f) {
  u32 u = __float_as_uint(f);
  u += 0x7fffu + ((u >> 16) & 1u);
  return (u16)(u >> 16);
}
DEV float bf2f(u16 h) { return __uint_as_float(((u32)h) << 16); }

DEV void gload_lds16(const void* g, void* l) {
  __builtin_amdgcn_global_load_lds(
      (__attribute__((address_space(1))) void*)(g),
      (__attribute__((address_space(3))) void*)(l), 16, 0, 0);
}

// 16B-unit XOR swizzle for pb rows (write+read must agree); col in u16 units.
DEV int swz8(int row, int lq) { return (lq ^ ((row >> 3) & 3)) * 8; }

// ---------------- fused transpose fp32 [K,N] -> bf16 [N,K], 11 matrices ----------------
struct TransDesc {
  const float* src[11];
  u16* dst[11];
  int K[11];
  int N[11];
};

__global__ __launch_bounds__(256) void k_transpose_all(TransDesc td) {
  int z = blockIdx.z;
  int K = td.K[z], N = td.N[z];
  int n0 = blockIdx.x * 32, k0 = blockIdx.y * 32;
  if (n0 >= N || k0 >= K) return;
  const float* W = td.src[z];
  u16* Wt = td.dst[z];
  __shared__ float tile[32][33];
  int c = threadIdx.x & 31, r0 = threadIdx.x >> 5;
#pragma unroll
  for (int i = 0; i < 4; ++i) {
    int r = r0 + i * 8;
    tile[r][c] = W[(size_t)(k0 + r) * N + (n0 + c)];
  }
  __syncthreads();
#pragma unroll
  for (int i = 0; i < 4; ++i) {
    int r = r0 + i * 8;
    Wt[(size_t)(n0 + r) * K + (k0 + c)] = f2bf(tile[c][r]);
  }
}

// ---------------- LN1 + token shift + 6 mixes -> bf16 ----------------
__global__ __launch_bounds__(256) void k_ln_shift(
    const float* __restrict__ x, const float* __restrict__ w, const float* __restrict__ bias,
    const float* __restrict__ cr, const float* __restrict__ cw, const float* __restrict__ ck,
    const float* __restrict__ cv, const float* __restrict__ ca, const float* __restrict__ cg,
    u16* __restrict__ XR, u16* __restrict__ XW, u16* __restrict__ XK,
    u16* __restrict__ XV, u16* __restrict__ XA, u16* __restrict__ XG) {
  int row = blockIdx.x;
  int t = row & (Tt - 1);
  int tid = threadIdx.x;
  int col = tid * 4;
  const float* xc = x + (size_t)row * Dd + col;
  f32x4 c = *(const f32x4*)xc;
  f32x4 p = {0.f, 0.f, 0.f, 0.f};
  bool hasprev = (t != 0);
  if (hasprev) p = *(const f32x4*)(xc - Dd);
  float s1 = 0, s2 = 0, s3 = 0, s4 = 0;
#pragma unroll
  for (int j = 0; j < 4; ++j) {
    s1 += c[j]; s2 += c[j] * c[j];
    s3 += p[j]; s4 += p[j] * p[j];
  }
#pragma unroll
  for (int m = 1; m < 64; m <<= 1) {
    s1 += __shfl_xor(s1, m, 64); s2 += __shfl_xor(s2, m, 64);
    s3 += __shfl_xor(s3, m, 64); s4 += __shfl_xor(s4, m, 64);
  }
  __shared__ float red[4][4];
  int wid = tid >> 6;
  if ((tid & 63) == 0) { red[wid][0] = s1; red[wid][1] = s2; red[wid][2] = s3; red[wid][3] = s4; }
  __syncthreads();
  s1 = red[0][0] + red[1][0] + red[2][0] + red[3][0];
  s2 = red[0][1] + red[1][1] + red[2][1] + red[3][1];
  s3 = red[0][2] + red[1][2] + red[2][2] + red[3][2];
  s4 = red[0][3] + red[1][3] + red[2][3] + red[3][3];
  const float invD = 1.f / (float)Dd;
  float mc = s1 * invD, vc = s2 * invD - mc * mc;
  float rc = rsqrtf(vc + 1e-5f);
  float mp = s3 * invD, vp = s4 * invD - mp * mp;
  float rp = rsqrtf(vp + 1e-5f);
  size_t ob = (size_t)row * Dd + col;
#pragma unroll
  for (int j = 0; j < 4; ++j) {
    int cc = col + j;
    float wj = w[cc], bj = bias[cc];
    float xn = (c[j] - mc) * rc * wj + bj;
    float xp = hasprev ? ((p[j] - mp) * rp * wj + bj) : 0.f;
    float d = xp - xn;
    XR[ob + j] = f2bf(xn + d * cr[cc]);
    XW[ob + j] = f2bf(xn + d * cw[cc]);
    XK[ob + j] = f2bf(xn + d * ck[cc]);
    XV[ob + j] = f2bf(xn + d * cv[cc]);
    XA[ob + j] = f2bf(xn + d * ca[cc]);
    XG[ob + j] = f2bf(xn + d * cg[cc]);
  }
}

// ---------------- bf16 MFMA GEMM, BK=32 ----------------
// EPI: 6=y+res->f32  7=y+bias+res->f32
template <int BM, int BN, int EPI, int GY>
__global__ __launch_bounds__(256) void k_gemm_bt(
    const u16* __restrict__ A, const u16* __restrict__ Bt,
    float* __restrict__ Cf,
    const float* __restrict__ aux, const float* __restrict__ res,
    int Ndim, int K) {
  constexpr int MR = BM / 32;
  constexpr int NR = BN / 32;
  __shared__ __align__(16) u16 lsA[BM * 32];
  __shared__ __align__(16) u16 lsB[BN * 32];
  int tid = threadIdx.x;
  int wid = tid >> 6, lane = tid & 63;
  int wr = wid >> 1, wc = wid & 1;
  int lrow = lane & 15, lk = lane >> 4;
  int d = blockIdx.x + 8 * blockIdx.y;
  int pan = d % GY, off = d / GY;
  int m0 = pan * BM, n0 = off * BN;
  f32x4 acc[MR][NR];
#pragma unroll
  for (int m = 0; m < MR; ++m)
#pragma unroll
    for (int n = 0; n < NR; ++n) acc[m][n] = (f32x4){0.f, 0.f, 0.f, 0.f};

  for (int kt = 0; kt < K; kt += 32) {
#pragma unroll
    for (int u = 0; u < BM / 64; ++u) {
      int e = u * 256 + tid;
      int row = e >> 2, kc = (e & 3) * 8;
      gload_lds16(A + (size_t)(m0 + row) * K + kt + kc, lsA + (size_t)e * 8);
    }
#pragma unroll
    for (int u = 0; u < BN / 64; ++u) {
      int e = u * 256 + tid;
      int row = e >> 2, kc = (e & 3) * 8;
      gload_lds16(Bt + (size_t)(n0 + row) * K + kt + kc, lsB + (size_t)e * 8);
    }
    __syncthreads();
    bf16x8 af[MR], bfv[NR];
#pragma unroll
    for (int m = 0; m < MR; ++m)
      af[m] = *(const bf16x8*)&lsA[(wr * (BM / 2) + m * 16 + lrow) * 32 + lk * 8];
#pragma unroll
    for (int n = 0; n < NR; ++n)
      bfv[n] = *(const bf16x8*)&lsB[(wc * (BN / 2) + n * 16 + lrow) * 32 + lk * 8];
#pragma unroll
    for (int m = 0; m < MR; ++m)
#pragma unroll
      for (int n = 0; n < NR; ++n)
        acc[m][n] = __builtin_amdgcn_mfma_f32_16x16x32_bf16(af[m], bfv[n], acc[m][n], 0, 0, 0);
    __syncthreads();
  }
#pragma unroll
  for (int m = 0; m < MR; ++m) {
    int rbase = m0 + wr * (BM / 2) + m * 16 + lk * 4;
#pragma unroll
    for (int n = 0; n < NR; ++n) {
      int col = n0 + wc * (BN / 2) + n * 16 + lrow;
#pragma unroll
      for (int j = 0; j < 4; ++j) {
        float v = acc[m][n][j];
        size_t idx = (size_t)(rbase + j) * Ndim + col;
        if constexpr (EPI == 6) { Cf[idx] = v + res[idx]; }
        else { Cf[idx] = v + aux[col] + res[idx]; }
      }
    }
  }
}

// ---------------- batched 3-GEMM: C = A @ Bt^T, N=1024 ----------------
// epi: 0=f32  4=wlog=-0.5-log1p(exp(-(w0+y)))  5=sigmoid(a0+y)
struct G3 {
  const u16* A[3];
  const u16* Bt[3];
  float* C[3];
  const float* aux[3];
  int K[3];
  int epi[3];
};

__global__ __launch_bounds__(256) void k_gemm3(G3 g) {
  constexpr int BM = 128, BN = 128, MR = 4, NR = 4;
  int d = blockIdx.x + 8 * blockIdx.y + 256 * blockIdx.z;
  int pan = d % 96, off = d / 96;
  int z = pan / 32;
  int m0 = (pan % 32) * BM, n0 = off * BN;
  const u16* A = g.A[z];
  const u16* Bt = g.Bt[z];
  float* Cf = g.C[z];
  const float* aux = g.aux[z];
  int K = g.K[z], epi = g.epi[z];
  __shared__ __align__(16) u16 lsA[BM * 32];
  __shared__ __align__(16) u16 lsB[BN * 32];
  int tid = threadIdx.x;
  int wid = tid >> 6, lane = tid & 63;
  int wr = wid >> 1, wc = wid & 1;
  int lrow = lane & 15, lk = lane >> 4;
  f32x4 acc[MR][NR];
#pragma unroll
  for (int m = 0; m < MR; ++m)
#pragma unroll
    for (int n = 0; n < NR; ++n) acc[m][n] = (f32x4){0.f, 0.f, 0.f, 0.f};

  for (int kt = 0; kt < K; kt += 32) {
#pragma unroll
    for (int u = 0; u < 2; ++u) {
      int e = u * 256 + tid;
      int row = e >> 2, kc = (e & 3) * 8;
      gload_lds16(A + (size_t)(m0 + row) * K + kt + kc, lsA + (size_t)e * 8);
      gload_lds16(Bt + (size_t)(n0 + row) * K + kt + kc, lsB + (size_t)e * 8);
    }
    __syncthreads();
    bf16x8 af[MR], bfv[NR];
#pragma unroll
    for (int m = 0; m < MR; ++m)
      af[m] = *(const bf16x8*)&lsA[(wr * 64 + m * 16 + lrow) * 32 + lk * 8];
#pragma unroll
    for (int n = 0; n < NR; ++n)
      bfv[n] = *(const bf16x8*)&lsB[(wc * 64 + n * 16 + lrow) * 32 + lk * 8];
#pragma unroll
    for (int m = 0; m < MR; ++m)
#pragma unroll
      for (int n = 0; n < NR; ++n)
        acc[m][n] = __builtin_amdgcn_mfma_f32_16x16x32_bf16(af[m], bfv[n], acc[m][n], 0, 0, 0);
    __syncthreads();
  }
#pragma unroll
  for (int m = 0; m < MR; ++m) {
    int rbase = m0 + wr * 64 + m * 16 + lk * 4;
#pragma unroll
    for (int n = 0; n < NR; ++n) {
      int col = n0 + wc * 64 + n * 16 + lrow;
#pragma unroll
      for (int j = 0; j < 4; ++j) {
        float v = acc[m][n][j];
        size_t idx = (size_t)(rbase + j) * 1024 + col;
        if (epi == 0) Cf[idx] = v;
        else if (epi == 4) Cf[idx] = -0.5f - logf(1.f + __expf(-(aux[col] + v)));
        else Cf[idx] = 1.f / (1.f + __expf(-(aux[col] + v)));
      }
    }
  }
}

// ---------------- fused first-stage LoRA GEMMs ----------------
__global__ __launch_bounds__(256) void k_lora1(
    const u16* __restrict__ XW, const u16* __restrict__ XA, const u16* __restrict__ XG,
    const u16* __restrict__ W1t, const u16* __restrict__ A1t, const u16* __restrict__ G1t,
    u16* __restrict__ HW, u16* __restrict__ HA, u16* __restrict__ HG) {
  constexpr int BM = 128, BN = 64, NR = 2, MR = 4, K = 1024;
  int z = blockIdx.z;
  int Ndim = (z == 2) ? 128 : 64;
  int n0 = blockIdx.x * BN;
  if (n0 >= Ndim) return;
  const u16* A = (z == 0) ? XW : (z == 1) ? XA : XG;
  const u16* Bt = (z == 0) ? W1t : (z == 1) ? A1t : G1t;
  u16* Cb = (z == 0) ? HW : (z == 1) ? HA : HG;
  __shared__ __align__(16) u16 lsA[BM * 32];
  __shared__ __align__(16) u16 lsB[BN * 32];
  int tid = threadIdx.x;
  int wid = tid >> 6, lane = tid & 63;
  int wr = wid >> 1, wc = wid & 1;
  int lrow = lane & 15, lk = lane >> 4;
  int m0 = blockIdx.y * BM;
  f32x4 acc[MR][NR];
#pragma unroll
  for (int m = 0; m < MR; ++m)
#pragma unroll
    for (int n = 0; n < NR; ++n) acc[m][n] = (f32x4){0.f, 0.f, 0.f, 0.f};
  for (int kt = 0; kt < K; kt += 32) {
#pragma unroll
    for (int u = 0; u < BM / 64; ++u) {
      int e = u * 256 + tid;
      int row = e >> 2, kc = (e & 3) * 8;
      gload_lds16(A + (size_t)(m0 + row) * K + kt + kc, lsA + (size_t)(u * 256 + wid * 64) * 8);
    }
    {
      int row = tid >> 2, kc = (tid & 3) * 8;
      gload_lds16(Bt + (size_t)(n0 + row) * K + kt + kc, lsB + (size_t)(wid * 64) * 8);
    }
    __syncthreads();
    bf16x8 af[MR], bfv[NR];
#pragma unroll
    for (int m = 0; m < MR; ++m)
      af[m] = *(const bf16x8*)&lsA[(wr * 64 + m * 16 + lrow) * 32 + lk * 8];
#pragma unroll
    for (int n = 0; n < NR; ++n)
      bfv[n] = *(const bf16x8*)&lsB[(wc * 32 + n * 16 + lrow) * 32 + lk * 8];
#pragma unroll
    for (int m = 0; m < MR; ++m)
#pragma unroll
      for (int n = 0; n < NR; ++n)
        acc[m][n] = __builtin_amdgcn_mfma_f32_16x16x32_bf16(af[m], bfv[n], acc[m][n], 0, 0, 0);
    __syncthreads();
  }
#pragma unroll
  for (int m = 0; m < MR; ++m) {
    int rbase = m0 + wr * 64 + m * 16 + lk * 4;
#pragma unroll
    for (int n = 0; n < NR; ++n) {
      int col = n0 + wc * 32 + n * 16 + lrow;
#pragma unroll
      for (int j = 0; j < 4; ++j) {
        float v = acc[m][n][j];
        float r = (z == 0) ? tanhf(v) : (z == 1) ? v : 1.f / (1.f + __expf(-v));
        Cb[(size_t)(rbase + j) * Ndim + col] = f2bf(r);
      }
    }
  }
}

// ================= chunked delta-rule scan (prep fused, parallel cumsum) =================
// TS packed tile (u16 units): M1[16][64] @0, M2 @1024, G1[16][32] @2048, G2[64][32] @2560, TOT 4608
static constexpr int TS_M1 = 0, TS_M2 = 1024, TS_G1 = 2048, TS_G2 = 2560, TS_TOT = 4608;

__global__ __launch_bounds__(256) void k_chunk(
    const float* __restrict__ WLOG, const float* __restrict__ KRAW,
    const float* __restrict__ Af, const float* __restrict__ kk_c,
    const float* __restrict__ ka_c,
    const float* __restrict__ R, const float* __restrict__ V,
    u16* __restrict__ TSg, u16* __restrict__ Opg, u16* __restrict__ Udg,
    float* __restrict__ ECg) {
  __shared__ __align__(16) float ela[17][64];
  __shared__ __align__(16) float e8r[64];
  __shared__ __align__(16) u16 Fkkb[16][72];
  __shared__ __align__(16) u16 Frb[16][72];
  __shared__ __align__(16) u16 Gab[16][72];
  __shared__ __align__(16) u16 Gk2b[16][72];
  __shared__ __align__(16) u16 pb[336][40];
  float* lwf = (float*)&pb[272][0];   // lw[17][64] overlay (dead after P1b)
  float* mf = (float*)&pb[272][0];    // matf [4][16][17] overlay (dead before T1n)
  float* gsum = (float*)&Fkkb[0][0];  // [4][64] cumsum scratch (Fkkb dead until P2)
  int bx = blockIdx.x;
  int c = bx & 63, bh = bx >> 6;
  int b = bh >> 4, h = bh & 15;
  int tid = threadIdx.x;
  int lane = tid & 63, w = tid >> 6;
  int lr = lane & 15, lq = lane >> 4;
  size_t tau = (size_t)bx;
  size_t rowbase = (size_t)(b * 1024 + c * 16) * 1024 + h * 64;

  // full zero-init rows 0-271 (swizzled half-written rows need their pad units zeroed)
  for (int i = tid; i < 272 * 16; i += 256)
    ((u32*)pb)[(i >> 4) * 20 + (i & 15)] = 0u;
  // P1a parallel cumsum: all 256 threads, 4 t-rows each (16 loads in flight)
  {
    int k = tid & 63, q = tid >> 6;
    const float* wp = WLOG + rowbase + k;
    float w0v = wp[(size_t)(4 * q + 0) * 1024];
    float w1v = wp[(size_t)(4 * q + 1) * 1024];
    float w2v = wp[(size_t)(4 * q + 2) * 1024];
    float w3v = wp[(size_t)(4 * q + 3) * 1024];
    float p0 = w0v, p1 = p0 + w1v, p2 = p1 + w2v, p3 = p2 + w3v;
    gsum[q * 64 + k] = p3;
    __syncthreads();
    float base = 0.f;
#pragma unroll
    for (int qq = 0; qq < 3; ++qq)
      if (qq < q) base += gsum[qq * 64 + k];
    if (q == 0) lwf[0 * 64 + k] = 0.f;
    lwf[(4 * q + 1) * 64 + k] = base + p0;
    lwf[(4 * q + 2) * 64 + k] = base + p1;
    lwf[(4 * q + 3) * 64 + k] = base + p2;
    lwf[(4 * q + 4) * 64 + k] = base + p3;
  }
  __syncthreads();
  // P1b exps about ref = lw[8]
  for (int i = tid; i < 17 * 64; i += 256) {
    int t = i >> 6, k = i & 63;
    ela[t][k] = expf(lwf[t * 64 + k] - lwf[8 * 64 + k]);
  }
  if (tid < 64) e8r[tid] = expf(lwf[8 * 64 + tid]);
  __syncthreads();
  // P2 fused prep (kk normalize) + operand builds + M1/M2/EC
  {
    int tt = tid >> 4, k0 = (tid & 15) * 4;
    size_t grow = rowbase + (size_t)tt * 1024 + k0;
    f32x4 kr = *(const f32x4*)(KRAW + grow);
    f32x4 av = *(const f32x4*)(Af + grow);
    f32x4 rv = *(const f32x4*)(R + grow);
    f32x4 kkc = *(const f32x4*)(kk_c + ((h * 64) + k0));
    f32x4 kac = *(const f32x4*)(ka_c + ((h * 64) + k0));
    f32x4 kk0 = kr * kkc;
    float ss = kk0[0] * kk0[0] + kk0[1] * kk0[1] + kk0[2] * kk0[2] + kk0[3] * kk0[3];
    ss += __shfl_xor(ss, 1, 64);
    ss += __shfl_xor(ss, 2, 64);
    ss += __shfl_xor(ss, 4, 64);
    ss += __shfl_xor(ss, 8, 64);
    float inv = 1.f / fmaxf(sqrtf(ss), 1e-12f);
    f32x4 ea = *(const f32x4*)&ela[tt][k0];
    f32x4 ea1 = *(const f32x4*)&ela[tt + 1][k0];
    f32x4 e84 = *(const f32x4*)&e8r[k0];
    u16 m1p[4], m2p[4], fk[4], fr[4], ga[4], gk[4];
#pragma unroll
    for (int j = 0; j < 4; ++j) {
      float kkv = kk0[j] * inv;
      float kkav = kkv * av[j];
      float kpv = kr[j] * (1.f + (av[j] - 1.f) * kac[j]);
      float fkk = kkv * ea[j];
      float frv = rv[j] * ea1[j];
      float eb1 = __builtin_amdgcn_rcpf(ea1[j]);
      fk[j] = f2bf(fkk);
      fr[j] = f2bf(frv);
      m1p[j] = f2bf(fkk * e84[j]);
      m2p[j] = f2bf(frv * e84[j]);
      ga[j] = f2bf(kkav * eb1);
      gk[j] = f2bf(kpv * eb1);
    }
    *(u32x2*)&Fkkb[tt][k0] = *(u32x2*)fk;
    *(u32x2*)&Frb[tt][k0] = *(u32x2*)fr;
    *(u32x2*)&Gab[tt][k0] = *(u32x2*)ga;
    *(u32x2*)&Gk2b[tt][k0] = *(u32x2*)gk;
    *(u32x2*)(TSg + tau * TS_TOT + TS_M1 + tt * 64 + k0) = *(u32x2*)m1p;
    *(u32x2*)(TSg + tau * TS_TOT + TS_M2 + tt * 64 + k0) = *(u32x2*)m2p;
    if (tid < 64) {
      f32x4 ec;
#pragma unroll
      for (int kt = 0; kt < 4; ++kt) {
        int kk2 = kt * 16 + (tid & 15);
        ec[kt] = ela[16][kk2] * e8r[kk2];
      }
      *(f32x4*)(ECg + tau * 256 + tid * 4) = ec;
    }
  }
  __syncthreads();
  // P3a k-major transposed builds (swizzled) — V direct from global
  {
    int k = tid & 63, tq = tid >> 6;
    float e16 = ela[16][k];
    u16 vt4[4], ad4[4], kd4[4];
#pragma unroll
    for (int i = 0; i < 4; ++i) {
      int tt = tq * 4 + i;
      float vv = V[rowbase + (size_t)tt * 1024 + k];
      vt4[i] = f2bf(vv);
      ad4[i] = f2bf(bf2f(Gab[tt][k]) * e16);
      kd4[i] = f2bf(bf2f(Gk2b[tt][k]) * e16);
    }
    int half = (tq & 1) * 4, unit = tq >> 1;
    *(u32x2*)&pb[k][(unit ^ ((k >> 3) & 3)) * 8 + half] = *(u32x2*)vt4;
    *(u32x2*)&pb[144 + k][(unit ^ (((144 + k) >> 3) & 3)) * 8 + half] = *(u32x2*)ad4;
    *(u32x2*)&pb[208 + k][(unit ^ (((208 + k) >> 3) & 3)) * 8 + half] = *(u32x2*)kd4;
  }
  // P3b C x C matrices via MFMA; wave w -> mat w (into mf overlay)
  {
    const u16* Ab = (w < 2) ? &Fkkb[0][0] : &Frb[0][0];
    const u16* Bb = (w & 1) ? &Gk2b[0][0] : &Gab[0][0];
    f32x4 d = {0.f, 0.f, 0.f, 0.f};
    bf16x8 a0 = *(const bf16x8*)(Ab + lr * 72 + lq * 8);
    bf16x8 a1 = *(const bf16x8*)(Ab + lr * 72 + 32 + lq * 8);
    bf16x8 b0 = *(const bf16x8*)(Bb + lr * 72 + lq * 8);
    bf16x8 b1 = *(const bf16x8*)(Bb + lr * 72 + 32 + lq * 8);
    d = __builtin_amdgcn_mfma_f32_16x16x32_bf16(a0, b0, d, 0, 0, 0);
    d = __builtin_amdgcn_mfma_f32_16x16x32_bf16(a1, b1, d, 0, 0, 0);
    bool strict = (w < 2);
#pragma unroll
    for (int j = 0; j < 4; ++j) {
      int rowt = lq * 4 + j, coli = lr;
      bool keep = strict ? (coli < rowt) : (coli <= rowt);
      mf[(w * 16 + rowt) * 17 + coli] = keep ? d[j] : 0.f;
    }
  }
  __syncthreads();
  // P4 Tinv solve (wave 0, 4-way partial sums to cut FMA chain) || P4.5 copies (waves 1-3)
  if (tid < 64) {
    float x[16];
#pragma unroll
    for (int i = 0; i < 16; ++i) x[i] = (i == lane) ? 1.f : 0.f;
#pragma unroll
    for (int i = 14; i >= 0; --i) {
      float s0 = 0.f, s1 = 0.f, s2 = 0.f, s3 = 0.f;
#pragma unroll
      for (int m = i + 1; m < 16; ++m) {
        float t = mf[m * 17 + i] * x[m];
        if ((m & 3) == 0) s0 += t;
        else if ((m & 3) == 1) s1 += t;
        else if ((m & 3) == 2) s2 += t;
        else s3 += t;
      }
      x[i] -= ((s0 + s1) + (s2 + s3));
    }
    if (lane < 16) {
#pragma unroll
      for (int i = 0; i < 16; ++i) {
        u16 v = f2bf(x[i]);
        pb[112 + i][lane] = v;
        pb[128 + lane][i] = v;
      }
    }
  } else {
    int id = tid - 64;
    for (int i = id; i < 768; i += 192) {
      int m = i >> 8, rem = i & 255, r = rem >> 4, cc = rem & 15;
      pb[64 + m * 16 + r][cc] = f2bf(mf[((1 + m) * 16 + r) * 17 + cc]);
    }
  }
  __syncthreads();
  // P5a: T1n = -(V @ Kkk^T)
  {
    int rv2 = 16 * w + lr;
    bf16x8 a = *(const bf16x8*)&pb[rv2][swz8(rv2, lq)];
    bf16x8 bb = *(const bf16x8*)&pb[64 + lr][lq * 8];
    f32x4 d = {0.f, 0.f, 0.f, 0.f};
    d = __builtin_amdgcn_mfma_f32_16x16x32_bf16(a, bb, d, 0, 0, 0);
#pragma unroll
    for (int j = 0; j < 4; ++j) {
      int rw = 272 + 16 * w + lq * 4 + j;
      pb[rw][lr] = f2bf(-d[j]);
      pb[rw][16 + lr] = 0;
    }
  }
  // P5b: Xp = T1n @ Tinv
  {
    bf16x8 a = *(const bf16x8*)&pb[272 + 16 * w + lr][lq * 8];
    bf16x8 bb = *(const bf16x8*)&pb[128 + lr][lq * 8];
    f32x4 d = {0.f, 0.f, 0.f, 0.f};
    d = __builtin_amdgcn_mfma_f32_16x16x32_bf16(a, bb, d, 0, 0, 0);
#pragma unroll
    for (int j = 0; j < 4; ++j) pb[272 + 16 * w + lq * 4 + j][lr] = f2bf(d[j]);
  }
  // P5c/P6/P7: G1 (wave0), G2 ntile w, Op mtile w, Ud mtile w
  {
    bf16x8 atv = *(const bf16x8*)&pb[112 + lr][lq * 8];
    if (w == 0) {
      bf16x8 bb = *(const bf16x8*)&pb[80 + lr][lq * 8];
      f32x4 d = {0.f, 0.f, 0.f, 0.f};
      d = __builtin_amdgcn_mfma_f32_16x16x32_bf16(atv, bb, d, 0, 0, 0);
      u16* g1g = TSg + tau * TS_TOT + TS_G1;
#pragma unroll
      for (int j = 0; j < 4; ++j) g1g[lr * 32 + lq * 4 + j] = f2bf(d[j]);
      *(u32x2*)(g1g + lr * 32 + 16 + lq * 4) = (u32x2){0u, 0u};
    }
    {
      int ra = 144 + 16 * w + lr;
      bf16x8 bb = *(const bf16x8*)&pb[ra][swz8(ra, lq)];
      f32x4 d = {0.f, 0.f, 0.f, 0.f};
      d = __builtin_amdgcn_mfma_f32_16x16x32_bf16(atv, bb, d, 0, 0, 0);
      u16* g2g = TSg + tau * TS_TOT + TS_G2;
#pragma unroll
      for (int j = 0; j < 4; ++j) g2g[(16 * w + lr) * 32 + lq * 4 + j] = f2bf(d[j]);
      *(u32x2*)(g2g + (16 * w + lr) * 32 + 16 + lq * 4) = (u32x2){0u, 0u};
    }
    int rv2 = 16 * w + lr;
    bf16x8 axp = *(const bf16x8*)&pb[272 + 16 * w + lr][lq * 8];
    bf16x8 avt = *(const bf16x8*)&pb[rv2][swz8(rv2, lq)];
    {
      bf16x8 bar = *(const bf16x8*)&pb[80 + lr][lq * 8];
      bf16x8 bkr = *(const bf16x8*)&pb[96 + lr][lq * 8];
      f32x4 d = {0.f, 0.f, 0.f, 0.f};
      d = __builtin_amdgcn_mfma_f32_16x16x32_bf16(axp, bar, d, 0, 0, 0);
      d = __builtin_amdgcn_mfma_f32_16x16x32_bf16(avt, bkr, d, 0, 0, 0);
      u16 o4[4];
#pragma unroll
      for (int j = 0; j < 4; ++j) o4[j] = f2bf(d[j]);
      *(u32x2*)(Opg + (tau * 256 + w * 64 + lane) * 4) = *(u32x2*)o4;
    }
#pragma unroll
    for (int nt = 0; nt < 4; ++nt) {
      int ra = 144 + 16 * nt + lr, rk2 = 208 + 16 * nt + lr;
      bf16x8 bad = *(const bf16x8*)&pb[ra][swz8(ra, lq)];
      bf16x8 bkd = *(const bf16x8*)&pb[rk2][swz8(rk2, lq)];
      f32x4 d = {0.f, 0.f, 0.f, 0.f};
      d = __builtin_amdgcn_mfma_f32_16x16x32_bf16(axp, bad, d, 0, 0, 0);
      d = __builtin_amdgcn_mfma_f32_16x16x32_bf16(avt, bkd, d, 0, 0, 0);
      u16 u4[4];
#pragma unroll
      for (int j = 0; j < 4; ++j) u4[j] = f2bf(d[j]);
      *(u32x2*)(Udg + (tau * 256 + w * 64 + lane) * 16 + nt * 4) = *(u32x2*)u4;
    }
  }
}

// ---------------- sequential chunk scan: 256 wgs x 1 wave ----------------
struct Frags {
  bf16x8 m10, m11, m20, m21, g1b, g2b0, g2b1, g2b2, g2b3;
  u32x4 ud0, ud1;
  u32x2 opu;
  f32x4 ef;
};

__global__ __launch_bounds__(64) void k_scan2(
    const u16* __restrict__ TSg, const u16* __restrict__ Opg,
    const u16* __restrict__ Udg, const float* __restrict__ ECg,
    float* __restrict__ O) {
  __shared__ __align__(16) u16 Sb[16][72];
  __shared__ __align__(16) u16 negb[16][40];
  int bx = blockIdx.x;
  int sw = (bx & 7) * 32 + (bx >> 3);
  int bh = sw >> 2, vs = sw & 3;
  int b = bh >> 4, h = bh & 15;
  int l = threadIdx.x;
  int lr = l & 15, lq = l >> 4;
  if (l < 16) {
    *(u32x4*)&negb[l][16] = (u32x4){0u, 0u, 0u, 0u};
    *(u32x4*)&negb[l][24] = (u32x4){0u, 0u, 0u, 0u};
  }
  f32x4 S[4];
#pragma unroll
  for (int kt = 0; kt < 4; ++kt) S[kt] = (f32x4){0.f, 0.f, 0.f, 0.f};

  auto loadF = [&](int cc) {
    Frags f;
    size_t tau = (size_t)(bh * 64 + cc);
    const u16* ts = TSg + tau * TS_TOT;
    f.m10 = *(const bf16x8*)(ts + TS_M1 + lr * 64 + lq * 8);
    f.m11 = *(const bf16x8*)(ts + TS_M1 + lr * 64 + 32 + lq * 8);
    f.m20 = *(const bf16x8*)(ts + TS_M2 + lr * 64 + lq * 8);
    f.m21 = *(const bf16x8*)(ts + TS_M2 + lr * 64 + 32 + lq * 8);
    f.g1b = *(const bf16x8*)(ts + TS_G1 + lr * 32 + lq * 8);
    f.g2b0 = *(const bf16x8*)(ts + TS_G2 + (0 * 16 + lr) * 32 + lq * 8);
    f.g2b1 = *(const bf16x8*)(ts + TS_G2 + (1 * 16 + lr) * 32 + lq * 8);
    f.g2b2 = *(const bf16x8*)(ts + TS_G2 + (2 * 16 + lr) * 32 + lq * 8);
    f.g2b3 = *(const bf16x8*)(ts + TS_G2 + (3 * 16 + lr) * 32 + lq * 8);
    f.ud0 = *(const u32x4*)(Udg + (tau * 256 + vs * 64 + l) * 16);
    f.ud1 = *(const u32x4*)(Udg + (tau * 256 + vs * 64 + l) * 16 + 8);
    f.opu = *(const u32x2*)(Opg + (tau * 256 + vs * 64 + l) * 4);
    f.ef = *(const f32x4*)(ECg + tau * 256 + l * 4);
    return f;
  };

  auto doChunk = [&](int c, const Frags& f) {
#pragma unroll
    for (int kt = 0; kt < 4; ++kt)
#pragma unroll
      for (int j = 0; j < 4; ++j) Sb[lq * 4 + j][kt * 16 + lr] = f2bf(S[kt][j]);
    bf16x8 a0 = *(const bf16x8*)&Sb[lr][lq * 8];
    bf16x8 a1 = *(const bf16x8*)&Sb[lr][32 + lq * 8];
    f32x4 s0b = {0.f, 0.f, 0.f, 0.f}, s0r = {0.f, 0.f, 0.f, 0.f};
    s0b = __builtin_amdgcn_mfma_f32_16x16x32_bf16(a0, f.m10, s0b, 0, 0, 0);
    s0b = __builtin_amdgcn_mfma_f32_16x16x32_bf16(a1, f.m11, s0b, 0, 0, 0);
    s0r = __builtin_amdgcn_mfma_f32_16x16x32_bf16(a0, f.m20, s0r, 0, 0, 0);
    s0r = __builtin_amdgcn_mfma_f32_16x16x32_bf16(a1, f.m21, s0r, 0, 0, 0);
#pragma unroll
    for (int j = 0; j < 4; ++j) negb[lq * 4 + j][lr] = f2bf(-s0b[j]);
    bf16x8 nb0 = *(const bf16x8*)&negb[lr][lq * 8];
    f32x4 o = __builtin_amdgcn_mfma_f32_16x16x32_bf16(nb0, f.g1b, s0r, 0, 0, 0);
    u16 op4[4];
    *(u32x2*)op4 = f.opu;
#pragma unroll
    for (int j = 0; j < 4; ++j) o[j] += bf2f(op4[j]);
    size_t orow = ((size_t)b * 1024 + c * 16 + lr) * 1024 + h * 64 + vs * 16 + lq * 4;
    *(f32x4*)(O + orow) = o;
    u16 udh[16];
    *(u32x4*)&udh[0] = f.ud0;
    *(u32x4*)&udh[8] = f.ud1;
    f32x4 cin0, cin1, cin2, cin3;
#pragma unroll
    for (int j = 0; j < 4; ++j) {
      cin0[j] = S[0][j] * f.ef[0] + bf2f(udh[0 * 4 + j]);
      cin1[j] = S[1][j] * f.ef[1] + bf2f(udh[1 * 4 + j]);
      cin2[j] = S[2][j] * f.ef[2] + bf2f(udh[2 * 4 + j]);
      cin3[j] = S[3][j] * f.ef[3] + bf2f(udh[3 * 4 + j]);
    }
    S[0] = __builtin_amdgcn_mfma_f32_16x16x32_bf16(nb0, f.g2b0, cin0, 0, 0, 0);
    S[1] = __builtin_amdgcn_mfma_f32_16x16x32_bf16(nb0, f.g2b1, cin1, 0, 0, 0);
    S[2] = __builtin_amdgcn_mfma_f32_16x16x32_bf16(nb0, f.g2b2, cin2, 0, 0, 0);
    S[3] = __builtin_amdgcn_mfma_f32_16x16x32_bf16(nb0, f.g2b3, cin3, 0, 0, 0);
  };

  Frags fA = loadF(0);
  Frags fB = loadF(1);
  for (int cp = 0; cp < 62; cp += 2) {
    doChunk(cp, fA);
    fA = loadF(cp + 2);
    doChunk(cp + 1, fB);
    fB = loadF(cp + 3);
  }
  doChunk(62, fA);
  doChunk(63, fB);
}

// ---------------- per-head groupnorm + bonus + gate -> bf16 (kp inline) ----------------
__global__ __launch_bounds__(256) void k_gn_gate(
    const float* __restrict__ O, const float* __restrict__ R,
    const float* __restrict__ KRAW, const float* __restrict__ Af,
    const float* __restrict__ ka_c,
    const float* __restrict__ V, const float* __restrict__ G,
    const float* __restrict__ r_k, const float* __restrict__ gn_w, const float* __restrict__ gn_b,
    u16* __restrict__ GT) {
  int row = blockIdx.x;
  int tid = threadIdx.x;
  int col = tid * 4;
  size_t idx = (size_t)row * Dd + col;
  f32x4 o = *(const f32x4*)(O + idx), r = *(const f32x4*)(R + idx),
        kr = *(const f32x4*)(KRAW + idx), av = *(const f32x4*)(Af + idx),
        v = *(const f32x4*)(V + idx), g = *(const f32x4*)(G + idx);
  f32x4 kac = *(const f32x4*)(ka_c + col);
  f32x4 rk = *(const f32x4*)(r_k + col), gw = *(const f32x4*)(gn_w + col),
        gb = *(const f32x4*)(gn_b + col);
  float so = 0, so2 = 0, sb = 0;
#pragma unroll
  for (int j = 0; j < 4; ++j) {
    float kp = kr[j] * (1.f + (av[j] - 1.f) * kac[j]);
    so += o[j]; so2 += o[j] * o[j]; sb += r[j] * kp * rk[j];
  }
#pragma unroll
  for (int m = 1; m < 16; m <<= 1) {
    so += __shfl_xor(so, m, 64);
    so2 += __shfl_xor(so2, m, 64);
    sb += __shfl_xor(sb, m, 64);
  }
  float mu = so * (1.f / 64.f);
  float var = so2 * (1.f / 64.f) - mu * mu;
  float rs = rsqrtf(var + 64e-5f);
#pragma unroll
  for (int j = 0; j < 4; ++j) {
    float on = (o[j] - mu) * rs * gw[j] + gb[j] + sb * v[j];
    GT[idx + j] = f2bf(on * g[j]);
  }
}

// ---------------- plain LN -> bf16 ----------------
__global__ __launch_bounds__(256) void k_ln(
    const float* __restrict__ X, const float* __restrict__ w, const float* __restrict__ bias,
    u16* __restrict__ OUT) {
  int row = blockIdx.x;
  int tid = threadIdx.x;
  int col = tid * 4;
  size_t idx = (size_t)row * Dd + col;
  f32x4 c = *(const f32x4*)(X + idx);
  float s1 = 0, s2 = 0;
#pragma unroll
  for (int j = 0; j < 4; ++j) { s1 += c[j]; s2 += c[j] * c[j]; }
#pragma unroll
  for (int m = 1; m < 64; m <<= 1) { s1 += __shfl_xor(s1, m, 64); s2 += __shfl_xor(s2, m, 64); }
  __shared__ float red[4][2];
  int wid = tid >> 6;
  if ((tid & 63) == 0) { red[wid][0] = s1; red[wid][1] = s2; }
  __syncthreads();
  s1 = red[0][0] + red[1][0] + red[2][0] + red[3][0];
  s2 = red[0][1] + red[1][1] + red[2][1] + red[3][1];
  const float invD = 1.f / (float)Dd;
  float mc = s1 * invD;
  float rc = rsqrtf(s2 * invD - mc * mc + 1e-5f);
#pragma unroll
  for (int j = 0; j < 4; ++j)
    OUT[idx + j] = f2bf((c[j] - mc) * rc * w[col + j] + bias[col + j]);
}

extern "C" void kernel_launch(void* const* d_in, const int* in_sizes, int n_in,
                              void* d_out, int out_size, void* d_ws, size_t ws_size,
                              hipStream_t stream) {
  const float* x    = (const float*)d_in[0];
  const float* ln1w = (const float*)d_in[1];
  const float* ln1b = (const float*)d_in[2];
  const float* ln2w = (const float*)d_in[3];
  const float* ln2b = (const float*)d_in[4];
  const float* xr_c = (const float*)d_in[5];
  const float* xw_c = (const float*)d_in[6];
  const float* xk_c = (const float*)d_in[7];
  const float* xv_c = (const float*)d_in[8];
  const float* xa_c = (const float*)d_in[9];
  const float* xg_c = (const float*)d_in[10];
  const float* Wr   = (const float*)d_in[11];
  const float* Wk   = (const float*)d_in[12];
  const float* Wv   = (const float*)d_in[13];
  const float* w0   = (const float*)d_in[14];
  const float* w1   = (const float*)d_in[15];
  const float* w2   = (const float*)d_in[16];
  const float* a0   = (const float*)d_in[17];
  const float* a1   = (const float*)d_in[18];
  const float* a2   = (const float*)d_in[19];
  const float* g1   = (const float*)d_in[20];
  const float* g2   = (const float*)d_in[21];
  const float* k_k  = (const float*)d_in[22];
  const float* k_a  = (const float*)d_in[23];
  const float* r_k  = (const float*)d_in[24];
  const float* gnw  = (const float*)d_in[25];
  const float* gnb  = (const float*)d_in[26];
  const float* Wo   = (const float*)d_in[27];
  const float* mlpw = (const float*)d_in[28];
  const float* mlpb = (const float*)d_in[29];

  char* ws = (char*)d_ws;
  const size_t MBy = 1024 * 1024;
  u16* WT_R  = (u16*)(ws + 0 * MBy);
  u16* WT_K  = (u16*)(ws + 2 * MBy);
  u16* WT_V  = (u16*)(ws + 4 * MBy);
  u16* WT_O  = (u16*)(ws + 6 * MBy);
  u16* WT_M  = (u16*)(ws + 8 * MBy);
  u16* WT_w1 = (u16*)(ws + 10 * MBy);
  u16* WT_a1 = (u16*)(ws + 10 * MBy + 128 * 1024);
  u16* WT_g1 = (u16*)(ws + 10 * MBy + 256 * 1024);
  u16* WT_w2 = (u16*)(ws + 10 * MBy + 512 * 1024);
  u16* WT_a2 = (u16*)(ws + 10 * MBy + 640 * 1024);
  u16* WT_g2 = (u16*)(ws + 10 * MBy + 768 * 1024);
  u16* XR = (u16*)(ws + 12 * MBy);
  u16* XW = (u16*)(ws + 20 * MBy);
  u16* XK = (u16*)(ws + 28 * MBy);
  u16* XV = (u16*)(ws + 36 * MBy);
  u16* XA = (u16*)(ws + 44 * MBy);
  u16* XG = (u16*)(ws + 52 * MBy);
  float* Rf    = (float*)(ws + 60 * MBy);
  float* KRAW  = (float*)(ws + 76 * MBy);
  float* WLOGf = (float*)(ws + 92 * MBy);
  float* Af    = (float*)(ws + 108 * MBy);
  float* Gf    = (float*)(ws + 124 * MBy);
  u16* HW = (u16*)(ws + 140 * MBy);
  u16* HA = (u16*)(ws + 140 * MBy + 512 * 1024);
  u16* HG = (u16*)(ws + 141 * MBy);
  // overlays
  float* Of   = (float*)(ws + 12 * MBy);   // over XR+XW (dead after QKV/lora1)
  float* X1   = (float*)(ws + 28 * MBy);   // over XK+XV (dead after QKV)
  u16* GT  = (u16*)(ws + 92 * MBy);        // over WLOGf (dead after k_chunk)
  u16* XN2 = (u16*)(ws + 116 * MBy);       // over Af upper half (dead after gn_gate)
  // chunked-scan tile arrays
  u16* TSg   = (u16*)(ws + 144 * MBy);
  u16* Udg   = (u16*)(ws + 188 * MBy);
  u16* Opg   = (u16*)(ws + 220 * MBy);
  float* ECg = (float*)(ws + 228 * MBy);
  float* OUT_X = (float*)d_out;
  float* OUT_V = (float*)d_out + (size_t)Mrows * Dd;

  dim3 blk(256);
  TransDesc td;
  td.src[0] = Wr;   td.dst[0] = WT_R;  td.K[0] = 1024; td.N[0] = 1024;
  td.src[1] = Wk;   td.dst[1] = WT_K;  td.K[1] = 1024; td.N[1] = 1024;
  td.src[2] = Wv;   td.dst[2] = WT_V;  td.K[2] = 1024; td.N[2] = 1024;
  td.src[3] = Wo;   td.dst[3] = WT_O;  td.K[3] = 1024; td.N[3] = 1024;
  td.src[4] = mlpw; td.dst[4] = WT_M;  td.K[4] = 1024; td.N[4] = 1024;
  td.src[5] = w1;   td.dst[5] = WT_w1; td.K[5] = 1024; td.N[5] = 64;
  td.src[6] = a1;   td.dst[6] = WT_a1; td.K[6] = 1024; td.N[6] = 64;
  td.src[7] = g1;   td.dst[7] = WT_g1; td.K[7] = 1024; td.N[7] = 128;
  td.src[8] = w2;   td.dst[8] = WT_w2; td.K[8] = 64;   td.N[8] = 1024;
  td.src[9] = a2;   td.dst[9] = WT_a2; td.K[9] = 64;   td.N[9] = 1024;
  td.src[10] = g2;  td.dst[10] = WT_g2; td.K[10] = 128; td.N[10] = 1024;
  k_transpose_all<<<dim3(32, 32, 11), blk, 0, stream>>>(td);

  k_ln_shift<<<Mrows, blk, 0, stream>>>(x, ln1w, ln1b, xr_c, xw_c, xk_c, xv_c, xa_c, xg_c,
                                        XR, XW, XK, XV, XA, XG);

  k_lora1<<<dim3(2, 32, 3), blk, 0, stream>>>(XW, XA, XG, WT_w1, WT_a1, WT_g1, HW, HA, HG);

  G3 gq;
  gq.A[0] = XR; gq.Bt[0] = WT_R; gq.C[0] = Rf;    gq.aux[0] = nullptr; gq.K[0] = 1024; gq.epi[0] = 0;
  gq.A[1] = XK; gq.Bt[1] = WT_K; gq.C[1] = KRAW;  gq.aux[1] = nullptr; gq.K[1] = 1024; gq.epi[1] = 0;
  gq.A[2] = XV; gq.Bt[2] = WT_V; gq.C[2] = OUT_V; gq.aux[2] = nullptr; gq.K[2] = 1024; gq.epi[2] = 0;
  k_gemm3<<<dim3(8, 32, 3), blk, 0, stream>>>(gq);

  G3 gw;
  gw.A[0] = HW; gw.Bt[0] = WT_w2; gw.C[0] = WLOGf; gw.aux[0] = w0;      gw.K[0] = 64;  gw.epi[0] = 4;
  gw.A[1] = HA; gw.Bt[1] = WT_a2; gw.C[1] = Af;    gw.aux[1] = a0;      gw.K[1] = 64;  gw.epi[1] = 5;
  gw.A[2] = HG; gw.Bt[2] = WT_g2; gw.C[2] = Gf;    gw.aux[2] = nullptr; gw.K[2] = 128; gw.epi[2] = 0;
  k_gemm3<<<dim3(8, 32, 3), blk, 0, stream>>>(gw);

  k_chunk<<<4096, blk, 0, stream>>>(WLOGf, KRAW, Af, k_k, k_a, Rf, OUT_V, TSg, Opg, Udg, ECg);
  k_scan2<<<256, dim3(64), 0, stream>>>(TSg, Opg, Udg, ECg, Of);
  k_gn_gate<<<Mrows, blk, 0, stream>>>(Of, Rf, KRAW, Af, k_a, OUT_V, Gf, r_k, gnw, gnb, GT);
  k_gemm_bt<64, 128, 6, 64><<<dim3(8, 64), blk, 0, stream>>>(GT, WT_O, X1, nullptr, x, 1024, 1024);
  k_ln<<<Mrows, blk, 0, stream>>>(X1, ln2w, ln2b, XN2);
  k_gemm_bt<64, 128, 7, 64><<<dim3(8, 64), blk, 0, stream>>>(XN2, WT_M, OUT_X, mlpb, X1, 1024, 1024);
}

// Round 23
// 278.304 us; speedup vs baseline: 1.1335x; 1.0181x over previous
//
#include <hip/hip_runtime.h>
#include <hip/hip_bf16.h>
#include <cstdint>

typedef unsigned short u16;
typedef unsigned int u32;
typedef __attribute__((__ext_vector_type__(4))) float f32x4;
typedef __attribute__((__ext_vector_type__(4))) u32 u32x4;
typedef __attribute__((__ext_vector_type__(2))) u32 u32x2;
typedef __attribute__((__ext_vector_type__(8))) __bf16 bf16x8;

#define DEV __device__ __forceinline__

static constexpr int Tt = 1024, Dd = 1024;
static constexpr int Mrows = 4096;  // B*T

DEV u16 f2bf(float f) {
  u32 u = __float_as_uint(f);
  u += 0x7fffu + ((u >> 16) & 1u);
  return (u16)(u >> 16);
}
DEV float bf2f(u16 h) { return __uint_as_float(((u32)h) << 16); }

DEV void gload_lds16(const void* g, void* l) {
  __builtin_amdgcn_global_load_lds(
      (__attribute__((address_space(1))) void*)(g),
      (__attribute__((address_space(3))) void*)(l), 16, 0, 0);
}

// 16B-unit XOR swizzle for pb rows (write+read must agree); col in u16 units.
DEV int swz8(int row, int lq) { return (lq ^ ((row >> 3) & 3)) * 8; }

// ---------------- fused transpose fp32 [K,N] -> bf16 [N,K], 11 matrices ----------------
struct TransDesc {
  const float* src[11];
  u16* dst[11];
  int K[11];
  int N[11];
};

__global__ __launch_bounds__(256) void k_transpose_all(TransDesc td) {
  int z = blockIdx.z;
  int K = td.K[z], N = td.N[z];
  int n0 = blockIdx.x * 32, k0 = blockIdx.y * 32;
  if (n0 >= N || k0 >= K) return;
  const float* W = td.src[z];
  u16* Wt = td.dst[z];
  __shared__ float tile[32][33];
  int c = threadIdx.x & 31, r0 = threadIdx.x >> 5;
#pragma unroll
  for (int i = 0; i < 4; ++i) {
    int r = r0 + i * 8;
    tile[r][c] = W[(size_t)(k0 + r) * N + (n0 + c)];
  }
  __syncthreads();
#pragma unroll
  for (int i = 0; i < 4; ++i) {
    int r = r0 + i * 8;
    Wt[(size_t)(n0 + r) * K + (k0 + c)] = f2bf(tile[c][r]);
  }
}

// ---------------- LN1 + token shift + 6 mixes -> bf16 ----------------
__global__ __launch_bounds__(256) void k_ln_shift(
    const float* __restrict__ x, const float* __restrict__ w, const float* __restrict__ bias,
    const float* __restrict__ cr, const float* __restrict__ cw, const float* __restrict__ ck,
    const float* __restrict__ cv, const float* __restrict__ ca, const float* __restrict__ cg,
    u16* __restrict__ XR, u16* __restrict__ XW, u16* __restrict__ XK,
    u16* __restrict__ XV, u16* __restrict__ XA, u16* __restrict__ XG) {
  int row = blockIdx.x;
  int t = row & (Tt - 1);
  int tid = threadIdx.x;
  int col = tid * 4;
  const float* xc = x + (size_t)row * Dd + col;
  f32x4 c = *(const f32x4*)xc;
  f32x4 p = {0.f, 0.f, 0.f, 0.f};
  bool hasprev = (t != 0);
  if (hasprev) p = *(const f32x4*)(xc - Dd);
  float s1 = 0, s2 = 0, s3 = 0, s4 = 0;
#pragma unroll
  for (int j = 0; j < 4; ++j) {
    s1 += c[j]; s2 += c[j] * c[j];
    s3 += p[j]; s4 += p[j] * p[j];
  }
#pragma unroll
  for (int m = 1; m < 64; m <<= 1) {
    s1 += __shfl_xor(s1, m, 64); s2 += __shfl_xor(s2, m, 64);
    s3 += __shfl_xor(s3, m, 64); s4 += __shfl_xor(s4, m, 64);
  }
  __shared__ float red[4][4];
  int wid = tid >> 6;
  if ((tid & 63) == 0) { red[wid][0] = s1; red[wid][1] = s2; red[wid][2] = s3; red[wid][3] = s4; }
  __syncthreads();
  s1 = red[0][0] + red[1][0] + red[2][0] + red[3][0];
  s2 = red[0][1] + red[1][1] + red[2][1] + red[3][1];
  s3 = red[0][2] + red[1][2] + red[2][2] + red[3][2];
  s4 = red[0][3] + red[1][3] + red[2][3] + red[3][3];
  const float invD = 1.f / (float)Dd;
  float mc = s1 * invD, vc = s2 * invD - mc * mc;
  float rc = rsqrtf(vc + 1e-5f);
  float mp = s3 * invD, vp = s4 * invD - mp * mp;
  float rp = rsqrtf(vp + 1e-5f);
  size_t ob = (size_t)row * Dd + col;
#pragma unroll
  for (int j = 0; j < 4; ++j) {
    int cc = col + j;
    float wj = w[cc], bj = bias[cc];
    float xn = (c[j] - mc) * rc * wj + bj;
    float xp = hasprev ? ((p[j] - mp) * rp * wj + bj) : 0.f;
    float d = xp - xn;
    XR[ob + j] = f2bf(xn + d * cr[cc]);
    XW[ob + j] = f2bf(xn + d * cw[cc]);
    XK[ob + j] = f2bf(xn + d * ck[cc]);
    XV[ob + j] = f2bf(xn + d * cv[cc]);
    XA[ob + j] = f2bf(xn + d * ca[cc]);
    XG[ob + j] = f2bf(xn + d * cg[cc]);
  }
}

// ---------------- bf16 MFMA GEMM, BK=32 ----------------
// EPI: 6=y+res->f32  7=y+bias+res->f32
template <int BM, int BN, int EPI, int GY>
__global__ __launch_bounds__(256) void k_gemm_bt(
    const u16* __restrict__ A, const u16* __restrict__ Bt,
    float* __restrict__ Cf,
    const float* __restrict__ aux, const float* __restrict__ res,
    int Ndim, int K) {
  constexpr int MR = BM / 32;
  constexpr int NR = BN / 32;
  __shared__ __align__(16) u16 lsA[BM * 32];
  __shared__ __align__(16) u16 lsB[BN * 32];
  int tid = threadIdx.x;
  int wid = tid >> 6, lane = tid & 63;
  int wr = wid >> 1, wc = wid & 1;
  int lrow = lane & 15, lk = lane >> 4;
  int d = blockIdx.x + 8 * blockIdx.y;
  int pan = d % GY, off = d / GY;
  int m0 = pan * BM, n0 = off * BN;
  f32x4 acc[MR][NR];
#pragma unroll
  for (int m = 0; m < MR; ++m)
#pragma unroll
    for (int n = 0; n < NR; ++n) acc[m][n] = (f32x4){0.f, 0.f, 0.f, 0.f};

  for (int kt = 0; kt < K; kt += 32) {
#pragma unroll
    for (int u = 0; u < BM / 64; ++u) {
      int e = u * 256 + tid;
      int row = e >> 2, kc = (e & 3) * 8;
      gload_lds16(A + (size_t)(m0 + row) * K + kt + kc, lsA + (size_t)e * 8);
    }
#pragma unroll
    for (int u = 0; u < BN / 64; ++u) {
      int e = u * 256 + tid;
      int row = e >> 2, kc = (e & 3) * 8;
      gload_lds16(Bt + (size_t)(n0 + row) * K + kt + kc, lsB + (size_t)e * 8);
    }
    __syncthreads();
    bf16x8 af[MR], bfv[NR];
#pragma unroll
    for (int m = 0; m < MR; ++m)
      af[m] = *(const bf16x8*)&lsA[(wr * (BM / 2) + m * 16 + lrow) * 32 + lk * 8];
#pragma unroll
    for (int n = 0; n < NR; ++n)
      bfv[n] = *(const bf16x8*)&lsB[(wc * (BN / 2) + n * 16 + lrow) * 32 + lk * 8];
#pragma unroll
    for (int m = 0; m < MR; ++m)
#pragma unroll
      for (int n = 0; n < NR; ++n)
        acc[m][n] = __builtin_amdgcn_mfma_f32_16x16x32_bf16(af[m], bfv[n], acc[m][n], 0, 0, 0);
    __syncthreads();
  }
#pragma unroll
  for (int m = 0; m < MR; ++m) {
    int rbase = m0 + wr * (BM / 2) + m * 16 + lk * 4;
#pragma unroll
    for (int n = 0; n < NR; ++n) {
      int col = n0 + wc * (BN / 2) + n * 16 + lrow;
#pragma unroll
      for (int j = 0; j < 4; ++j) {
        float v = acc[m][n][j];
        size_t idx = (size_t)(rbase + j) * Ndim + col;
        if constexpr (EPI == 6) { Cf[idx] = v + res[idx]; }
        else { Cf[idx] = v + aux[col] + res[idx]; }
      }
    }
  }
}

// ---------------- batched 6-GEMM (QKV + 2nd-stage LoRA): C = A @ Bt^T, N=1024, f32 out ----------------
// epi: 0=f32  4=wlog=-0.5-log1p(exp(-(w0+y)))  5=sigmoid(a0+y)
struct G6 {
  const u16* A[6];
  const u16* Bt[6];
  float* C[6];
  const float* aux[6];
  int K[6];
  int epi[6];
};

__global__ __launch_bounds__(256) void k_gemm6(G6 g) {
  constexpr int BM = 128, BN = 128, MR = 4, NR = 4;
  int z = blockIdx.z;
  int d2 = blockIdx.x + 8 * blockIdx.y;      // 0..255
  int pan = d2 & 31, off = d2 >> 5;          // 32 m-panels x 8 n-offs
  int m0 = pan * BM, n0 = off * BN;
  const u16* A = g.A[z];
  const u16* Bt = g.Bt[z];
  float* Cf = g.C[z];
  const float* aux = g.aux[z];
  int K = g.K[z], epi = g.epi[z];
  __shared__ __align__(16) u16 lsA[BM * 32];
  __shared__ __align__(16) u16 lsB[BN * 32];
  int tid = threadIdx.x;
  int wid = tid >> 6, lane = tid & 63;
  int wr = wid >> 1, wc = wid & 1;
  int lrow = lane & 15, lk = lane >> 4;
  f32x4 acc[MR][NR];
#pragma unroll
  for (int m = 0; m < MR; ++m)
#pragma unroll
    for (int n = 0; n < NR; ++n) acc[m][n] = (f32x4){0.f, 0.f, 0.f, 0.f};

  for (int kt = 0; kt < K; kt += 32) {
#pragma unroll
    for (int u = 0; u < 2; ++u) {
      int e = u * 256 + tid;
      int row = e >> 2, kc = (e & 3) * 8;
      gload_lds16(A + (size_t)(m0 + row) * K + kt + kc, lsA + (size_t)e * 8);
      gload_lds16(Bt + (size_t)(n0 + row) * K + kt + kc, lsB + (size_t)e * 8);
    }
    __syncthreads();
    bf16x8 af[MR], bfv[NR];
#pragma unroll
    for (int m = 0; m < MR; ++m)
      af[m] = *(const bf16x8*)&lsA[(wr * 64 + m * 16 + lrow) * 32 + lk * 8];
#pragma unroll
    for (int n = 0; n < NR; ++n)
      bfv[n] = *(const bf16x8*)&lsB[(wc * 64 + n * 16 + lrow) * 32 + lk * 8];
#pragma unroll
    for (int m = 0; m < MR; ++m)
#pragma unroll
      for (int n = 0; n < NR; ++n)
        acc[m][n] = __builtin_amdgcn_mfma_f32_16x16x32_bf16(af[m], bfv[n], acc[m][n], 0, 0, 0);
    __syncthreads();
  }
#pragma unroll
  for (int m = 0; m < MR; ++m) {
    int rbase = m0 + wr * 64 + m * 16 + lk * 4;
#pragma unroll
    for (int n = 0; n < NR; ++n) {
      int col = n0 + wc * 64 + n * 16 + lrow;
#pragma unroll
      for (int j = 0; j < 4; ++j) {
        float v = acc[m][n][j];
        size_t idx = (size_t)(rbase + j) * 1024 + col;
        if (epi == 0) Cf[idx] = v;
        else if (epi == 4) Cf[idx] = -0.5f - logf(1.f + __expf(-(aux[col] + v)));
        else Cf[idx] = 1.f / (1.f + __expf(-(aux[col] + v)));
      }
    }
  }
}

// ---------------- fused first-stage LoRA GEMMs ----------------
__global__ __launch_bounds__(256) void k_lora1(
    const u16* __restrict__ XW, const u16* __restrict__ XA, const u16* __restrict__ XG,
    const u16* __restrict__ W1t, const u16* __restrict__ A1t, const u16* __restrict__ G1t,
    u16* __restrict__ HW, u16* __restrict__ HA, u16* __restrict__ HG) {
  constexpr int BM = 128, BN = 64, NR = 2, MR = 4, K = 1024;
  int z = blockIdx.z;
  int Ndim = (z == 2) ? 128 : 64;
  int n0 = blockIdx.x * BN;
  if (n0 >= Ndim) return;
  const u16* A = (z == 0) ? XW : (z == 1) ? XA : XG;
  const u16* Bt = (z == 0) ? W1t : (z == 1) ? A1t : G1t;
  u16* Cb = (z == 0) ? HW : (z == 1) ? HA : HG;
  __shared__ __align__(16) u16 lsA[BM * 32];
  __shared__ __align__(16) u16 lsB[BN * 32];
  int tid = threadIdx.x;
  int wid = tid >> 6, lane = tid & 63;
  int wr = wid >> 1, wc = wid & 1;
  int lrow = lane & 15, lk = lane >> 4;
  int m0 = blockIdx.y * BM;
  f32x4 acc[MR][NR];
#pragma unroll
  for (int m = 0; m < MR; ++m)
#pragma unroll
    for (int n = 0; n < NR; ++n) acc[m][n] = (f32x4){0.f, 0.f, 0.f, 0.f};
  for (int kt = 0; kt < K; kt += 32) {
#pragma unroll
    for (int u = 0; u < BM / 64; ++u) {
      int e = u * 256 + tid;
      int row = e >> 2, kc = (e & 3) * 8;
      gload_lds16(A + (size_t)(m0 + row) * K + kt + kc, lsA + (size_t)(u * 256 + wid * 64) * 8);
    }
    {
      int row = tid >> 2, kc = (tid & 3) * 8;
      gload_lds16(Bt + (size_t)(n0 + row) * K + kt + kc, lsB + (size_t)(wid * 64) * 8);
    }
    __syncthreads();
    bf16x8 af[MR], bfv[NR];
#pragma unroll
    for (int m = 0; m < MR; ++m)
      af[m] = *(const bf16x8*)&lsA[(wr * 64 + m * 16 + lrow) * 32 + lk * 8];
#pragma unroll
    for (int n = 0; n < NR; ++n)
      bfv[n] = *(const bf16x8*)&lsB[(wc * 32 + n * 16 + lrow) * 32 + lk * 8];
#pragma unroll
    for (int m = 0; m < MR; ++m)
#pragma unroll
      for (int n = 0; n < NR; ++n)
        acc[m][n] = __builtin_amdgcn_mfma_f32_16x16x32_bf16(af[m], bfv[n], acc[m][n], 0, 0, 0);
    __syncthreads();
  }
#pragma unroll
  for (int m = 0; m < MR; ++m) {
    int rbase = m0 + wr * 64 + m * 16 + lk * 4;
#pragma unroll
    for (int n = 0; n < NR; ++n) {
      int col = n0 + wc * 32 + n * 16 + lrow;
#pragma unroll
      for (int j = 0; j < 4; ++j) {
        float v = acc[m][n][j];
        float r = (z == 0) ? tanhf(v) : (z == 1) ? v : 1.f / (1.f + __expf(-v));
        Cb[(size_t)(rbase + j) * Ndim + col] = f2bf(r);
      }
    }
  }
}

// ================= chunked delta-rule scan (prep fused, parallel cumsum) =================
// TS packed tile (u16 units): M1[16][64] @0, M2 @1024, G1[16][32] @2048, G2[64][32] @2560, TOT 4608
static constexpr int TS_M1 = 0, TS_M2 = 1024, TS_G1 = 2048, TS_G2 = 2560, TS_TOT = 4608;

__global__ __launch_bounds__(256) void k_chunk(
    const float* __restrict__ WLOG, const float* __restrict__ KRAW,
    const float* __restrict__ Af, const float* __restrict__ kk_c,
    const float* __restrict__ ka_c,
    const float* __restrict__ R, const float* __restrict__ V,
    u16* __restrict__ TSg, u16* __restrict__ Opg, u16* __restrict__ Udg,
    float* __restrict__ ECg) {
  __shared__ __align__(16) float ela[17][64];
  __shared__ __align__(16) float e8r[64];
  __shared__ __align__(16) u16 Fkkb[16][72];
  __shared__ __align__(16) u16 Frb[16][72];
  __shared__ __align__(16) u16 Gab[16][72];
  __shared__ __align__(16) u16 Gk2b[16][72];
  __shared__ __align__(16) u16 pb[336][40];
  float* lwf = (float*)&pb[272][0];   // lw[17][64] overlay (dead after P1b)
  float* mf = (float*)&pb[272][0];    // matf [4][16][17] overlay (dead before T1n)
  float* gsum = (float*)&Fkkb[0][0];  // [4][64] cumsum scratch (Fkkb dead until P2)
  int bx = blockIdx.x;
  int c = bx & 63, bh = bx >> 6;
  int b = bh >> 4, h = bh & 15;
  int tid = threadIdx.x;
  int lane = tid & 63, w = tid >> 6;
  int lr = lane & 15, lq = lane >> 4;
  size_t tau = (size_t)bx;
  size_t rowbase = (size_t)(b * 1024 + c * 16) * 1024 + h * 64;

  // full zero-init rows 0-271 (swizzled half-written rows need their pad units zeroed)
  for (int i = tid; i < 272 * 16; i += 256)
    ((u32*)pb)[(i >> 4) * 20 + (i & 15)] = 0u;
  // P1a parallel cumsum: all 256 threads, 4 t-rows each (16 loads in flight)
  {
    int k = tid & 63, q = tid >> 6;
    const float* wp = WLOG + rowbase + k;
    float w0v = wp[(size_t)(4 * q + 0) * 1024];
    float w1v = wp[(size_t)(4 * q + 1) * 1024];
    float w2v = wp[(size_t)(4 * q + 2) * 1024];
    float w3v = wp[(size_t)(4 * q + 3) * 1024];
    float p0 = w0v, p1 = p0 + w1v, p2 = p1 + w2v, p3 = p2 + w3v;
    gsum[q * 64 + k] = p3;
    __syncthreads();
    float base = 0.f;
#pragma unroll
    for (int qq = 0; qq < 3; ++qq)
      if (qq < q) base += gsum[qq * 64 + k];
    if (q == 0) lwf[0 * 64 + k] = 0.f;
    lwf[(4 * q + 1) * 64 + k] = base + p0;
    lwf[(4 * q + 2) * 64 + k] = base + p1;
    lwf[(4 * q + 3) * 64 + k] = base + p2;
    lwf[(4 * q + 4) * 64 + k] = base + p3;
  }
  __syncthreads();
  // P1b exps about ref = lw[8]
  for (int i = tid; i < 17 * 64; i += 256) {
    int t = i >> 6, k = i & 63;
    ela[t][k] = expf(lwf[t * 64 + k] - lwf[8 * 64 + k]);
  }
  if (tid < 64) e8r[tid] = expf(lwf[8 * 64 + tid]);
  __syncthreads();
  // P2 fused prep (kk normalize) + operand builds + M1/M2/EC
  {
    int tt = tid >> 4, k0 = (tid & 15) * 4;
    size_t grow = rowbase + (size_t)tt * 1024 + k0;
    f32x4 kr = *(const f32x4*)(KRAW + grow);
    f32x4 av = *(const f32x4*)(Af + grow);
    f32x4 rv = *(const f32x4*)(R + grow);
    f32x4 kkc = *(const f32x4*)(kk_c + ((h * 64) + k0));
    f32x4 kac = *(const f32x4*)(ka_c + ((h * 64) + k0));
    f32x4 kk0 = kr * kkc;
    float ss = kk0[0] * kk0[0] + kk0[1] * kk0[1] + kk0[2] * kk0[2] + kk0[3] * kk0[3];
    ss += __shfl_xor(ss, 1, 64);
    ss += __shfl_xor(ss, 2, 64);
    ss += __shfl_xor(ss, 4, 64);
    ss += __shfl_xor(ss, 8, 64);
    float inv = 1.f / fmaxf(sqrtf(ss), 1e-12f);
    f32x4 ea = *(const f32x4*)&ela[tt][k0];
    f32x4 ea1 = *(const f32x4*)&ela[tt + 1][k0];
    f32x4 e84 = *(const f32x4*)&e8r[k0];
    u16 m1p[4], m2p[4], fk[4], fr[4], ga[4], gk[4];
#pragma unroll
    for (int j = 0; j < 4; ++j) {
      float kkv = kk0[j] * inv;
      float kkav = kkv * av[j];
      float kpv = kr[j] * (1.f + (av[j] - 1.f) * kac[j]);
      float fkk = kkv * ea[j];
      float frv = rv[j] * ea1[j];
      float eb1 = __builtin_amdgcn_rcpf(ea1[j]);
      fk[j] = f2bf(fkk);
      fr[j] = f2bf(frv);
      m1p[j] = f2bf(fkk * e84[j]);
      m2p[j] = f2bf(frv * e84[j]);
      ga[j] = f2bf(kkav * eb1);
      gk[j] = f2bf(kpv * eb1);
    }
    *(u32x2*)&Fkkb[tt][k0] = *(u32x2*)fk;
    *(u32x2*)&Frb[tt][k0] = *(u32x2*)fr;
    *(u32x2*)&Gab[tt][k0] = *(u32x2*)ga;
    *(u32x2*)&Gk2b[tt][k0] = *(u32x2*)gk;
    *(u32x2*)(TSg + tau * TS_TOT + TS_M1 + tt * 64 + k0) = *(u32x2*)m1p;
    *(u32x2*)(TSg + tau * TS_TOT + TS_M2 + tt * 64 + k0) = *(u32x2*)m2p;
    if (tid < 64) {
      f32x4 ec;
#pragma unroll
      for (int kt = 0; kt < 4; ++kt) {
        int kk2 = kt * 16 + (tid & 15);
        ec[kt] = ela[16][kk2] * e8r[kk2];
      }
      *(f32x4*)(ECg + tau * 256 + tid * 4) = ec;
    }
  }
  __syncthreads();
  // P3a k-major transposed builds (swizzled) — V direct from global
  {
    int k = tid & 63, tq = tid >> 6;
    float e16 = ela[16][k];
    u16 vt4[4], ad4[4], kd4[4];
#pragma unroll
    for (int i = 0; i < 4; ++i) {
      int tt = tq * 4 + i;
      float vv = V[rowbase + (size_t)tt * 1024 + k];
      vt4[i] = f2bf(vv);
      ad4[i] = f2bf(bf2f(Gab[tt][k]) * e16);
      kd4[i] = f2bf(bf2f(Gk2b[tt][k]) * e16);
    }
    int half = (tq & 1) * 4, unit = tq >> 1;
    *(u32x2*)&pb[k][(unit ^ ((k >> 3) & 3)) * 8 + half] = *(u32x2*)vt4;
    *(u32x2*)&pb[144 + k][(unit ^ (((144 + k) >> 3) & 3)) * 8 + half] = *(u32x2*)ad4;
    *(u32x2*)&pb[208 + k][(unit ^ (((208 + k) >> 3) & 3)) * 8 + half] = *(u32x2*)kd4;
  }
  // P3b C x C matrices via MFMA; wave w -> mat w (into mf overlay)
  {
    const u16* Ab = (w < 2) ? &Fkkb[0][0] : &Frb[0][0];
    const u16* Bb = (w & 1) ? &Gk2b[0][0] : &Gab[0][0];
    f32x4 d = {0.f, 0.f, 0.f, 0.f};
    bf16x8 a0 = *(const bf16x8*)(Ab + lr * 72 + lq * 8);
    bf16x8 a1 = *(const bf16x8*)(Ab + lr * 72 + 32 + lq * 8);
    bf16x8 b0 = *(const bf16x8*)(Bb + lr * 72 + lq * 8);
    bf16x8 b1 = *(const bf16x8*)(Bb + lr * 72 + 32 + lq * 8);
    d = __builtin_amdgcn_mfma_f32_16x16x32_bf16(a0, b0, d, 0, 0, 0);
    d = __builtin_amdgcn_mfma_f32_16x16x32_bf16(a1, b1, d, 0, 0, 0);
    bool strict = (w < 2);
#pragma unroll
    for (int j = 0; j < 4; ++j) {
      int rowt = lq * 4 + j, coli = lr;
      bool keep = strict ? (coli < rowt) : (coli <= rowt);
      mf[(w * 16 + rowt) * 17 + coli] = keep ? d[j] : 0.f;
    }
  }
  __syncthreads();
  // P4 Tinv solve (wave 0, 4-way partial sums) || P4.5 f32->bf16 mat copies (waves 1-3)
  if (tid < 64) {
    float x[16];
#pragma unroll
    for (int i = 0; i < 16; ++i) x[i] = (i == lane) ? 1.f : 0.f;
#pragma unroll
    for (int i = 14; i >= 0; --i) {
      float s0 = 0.f, s1 = 0.f, s2 = 0.f, s3 = 0.f;
#pragma unroll
      for (int m = i + 1; m < 16; ++m) {
        float t = mf[m * 17 + i] * x[m];
        if ((m & 3) == 0) s0 += t;
        else if ((m & 3) == 1) s1 += t;
        else if ((m & 3) == 2) s2 += t;
        else s3 += t;
      }
      x[i] -= ((s0 + s1) + (s2 + s3));
    }
    if (lane < 16) {
#pragma unroll
      for (int i = 0; i < 16; ++i) {
        u16 v = f2bf(x[i]);
        pb[112 + i][lane] = v;
        pb[128 + lane][i] = v;
      }
    }
  } else {
    int id = tid - 64;
    for (int i = id; i < 768; i += 192) {
      int m = i >> 8, rem = i & 255, r = rem >> 4, cc = rem & 15;
      pb[64 + m * 16 + r][cc] = f2bf(mf[((1 + m) * 16 + r) * 17 + cc]);
    }
  }
  __syncthreads();
  // P5a: T1n = -(V @ Kkk^T)
  {
    int rv2 = 16 * w + lr;
    bf16x8 a = *(const bf16x8*)&pb[rv2][swz8(rv2, lq)];
    bf16x8 bb = *(const bf16x8*)&pb[64 + lr][lq * 8];
    f32x4 d = {0.f, 0.f, 0.f, 0.f};
    d = __builtin_amdgcn_mfma_f32_16x16x32_bf16(a, bb, d, 0, 0, 0);
#pragma unroll
    for (int j = 0; j < 4; ++j) {
      int rw = 272 + 16 * w + lq * 4 + j;
      pb[rw][lr] = f2bf(-d[j]);
      pb[rw][16 + lr] = 0;
    }
  }
  // P5b: Xp = T1n @ Tinv
  {
    bf16x8 a = *(const bf16x8*)&pb[272 + 16 * w + lr][lq * 8];
    bf16x8 bb = *(const bf16x8*)&pb[128 + lr][lq * 8];
    f32x4 d = {0.f, 0.f, 0.f, 0.f};
    d = __builtin_amdgcn_mfma_f32_16x16x32_bf16(a, bb, d, 0, 0, 0);
#pragma unroll
    for (int j = 0; j < 4; ++j) pb[272 + 16 * w + lq * 4 + j][lr] = f2bf(d[j]);
  }
  // P5c/P6/P7: G1 (wave0), G2 ntile w, Op mtile w, Ud mtile w
  {
    bf16x8 atv = *(const bf16x8*)&pb[112 + lr][lq * 8];
    if (w == 0) {
      bf16x8 bb = *(const bf16x8*)&pb[80 + lr][lq * 8];
      f32x4 d = {0.f, 0.f, 0.f, 0.f};
      d = __builtin_amdgcn_mfma_f32_16x16x32_bf16(atv, bb, d, 0, 0, 0);
      u16* g1g = TSg + tau * TS_TOT + TS_G1;
#pragma unroll
      for (int j = 0; j < 4; ++j) g1g[lr * 32 + lq * 4 + j] = f2bf(d[j]);
      *(u32x2*)(g1g + lr * 32 + 16 + lq * 4) = (u32x2){0u, 0u};
    }
    {
      int ra = 144 + 16 * w + lr;
      bf16x8 bb = *(const bf16x8*)&pb[ra][swz8(ra, lq)];
      f32x4 d = {0.f, 0.f, 0.f, 0.f};
      d = __builtin_amdgcn_mfma_f32_16x16x32_bf16(atv, bb, d, 0, 0, 0);
      u16* g2g = TSg + tau * TS_TOT + TS_G2;
#pragma unroll
      for (int j = 0; j < 4; ++j) g2g[(16 * w + lr) * 32 + lq * 4 + j] = f2bf(d[j]);
      *(u32x2*)(g2g + (16 * w + lr) * 32 + 16 + lq * 4) = (u32x2){0u, 0u};
    }
    int rv2 = 16 * w + lr;
    bf16x8 axp = *(const bf16x8*)&pb[272 + 16 * w + lr][lq * 8];
    bf16x8 avt = *(const bf16x8*)&pb[rv2][swz8(rv2, lq)];
    {
      bf16x8 bar = *(const bf16x8*)&pb[80 + lr][lq * 8];
      bf16x8 bkr = *(const bf16x8*)&pb[96 + lr][lq * 8];
      f32x4 d = {0.f, 0.f, 0.f, 0.f};
      d = __builtin_amdgcn_mfma_f32_16x16x32_bf16(axp, bar, d, 0, 0, 0);
      d = __builtin_amdgcn_mfma_f32_16x16x32_bf16(avt, bkr, d, 0, 0, 0);
      u16 o4[4];
#pragma unroll
      for (int j = 0; j < 4; ++j) o4[j] = f2bf(d[j]);
      *(u32x2*)(Opg + (tau * 256 + w * 64 + lane) * 4) = *(u32x2*)o4;
    }
#pragma unroll
    for (int nt = 0; nt < 4; ++nt) {
      int ra = 144 + 16 * nt + lr, rk2 = 208 + 16 * nt + lr;
      bf16x8 bad = *(const bf16x8*)&pb[ra][swz8(ra, lq)];
      bf16x8 bkd = *(const bf16x8*)&pb[rk2][swz8(rk2, lq)];
      f32x4 d = {0.f, 0.f, 0.f, 0.f};
      d = __builtin_amdgcn_mfma_f32_16x16x32_bf16(axp, bad, d, 0, 0, 0);
      d = __builtin_amdgcn_mfma_f32_16x16x32_bf16(avt, bkd, d, 0, 0, 0);
      u16 u4[4];
#pragma unroll
      for (int j = 0; j < 4; ++j) u4[j] = f2bf(d[j]);
      *(u32x2*)(Udg + (tau * 256 + w * 64 + lane) * 16 + nt * 4) = *(u32x2*)u4;
    }
  }
}

// ---------------- sequential chunk scan: 256 wgs x 1 wave ----------------
struct Frags {
  bf16x8 m10, m11, m20, m21, g1b, g2b0, g2b1, g2b2, g2b3;
  u32x4 ud0, ud1;
  u32x2 opu;
  f32x4 ef;
};

__global__ __launch_bounds__(64) void k_scan2(
    const u16* __restrict__ TSg, const u16* __restrict__ Opg,
    const u16* __restrict__ Udg, const float* __restrict__ ECg,
    float* __restrict__ O) {
  __shared__ __align__(16) u16 Sb[16][72];
  __shared__ __align__(16) u16 negb[16][40];
  int bx = blockIdx.x;
  int sw = (bx & 7) * 32 + (bx >> 3);
  int bh = sw >> 2, vs = sw & 3;
  int b = bh >> 4, h = bh & 15;
  int l = threadIdx.x;
  int lr = l & 15, lq = l >> 4;
  if (l < 16) {
    *(u32x4*)&negb[l][16] = (u32x4){0u, 0u, 0u, 0u};
    *(u32x4*)&negb[l][24] = (u32x4){0u, 0u, 0u, 0u};
  }
  f32x4 S[4];
#pragma unroll
  for (int kt = 0; kt < 4; ++kt) S[kt] = (f32x4){0.f, 0.f, 0.f, 0.f};

  auto loadF = [&](int cc) {
    Frags f;
    size_t tau = (size_t)(bh * 64 + cc);
    const u16* ts = TSg + tau * TS_TOT;
    f.m10 = *(const bf16x8*)(ts + TS_M1 + lr * 64 + lq * 8);
    f.m11 = *(const bf16x8*)(ts + TS_M1 + lr * 64 + 32 + lq * 8);
    f.m20 = *(const bf16x8*)(ts + TS_M2 + lr * 64 + lq * 8);
    f.m21 = *(const bf16x8*)(ts + TS_M2 + lr * 64 + 32 + lq * 8);
    f.g1b = *(const bf16x8*)(ts + TS_G1 + lr * 32 + lq * 8);
    f.g2b0 = *(const bf16x8*)(ts + TS_G2 + (0 * 16 + lr) * 32 + lq * 8);
    f.g2b1 = *(const bf16x8*)(ts + TS_G2 + (1 * 16 + lr) * 32 + lq * 8);
    f.g2b2 = *(const bf16x8*)(ts + TS_G2 + (2 * 16 + lr) * 32 + lq * 8);
    f.g2b3 = *(const bf16x8*)(ts + TS_G2 + (3 * 16 + lr) * 32 + lq * 8);
    f.ud0 = *(const u32x4*)(Udg + (tau * 256 + vs * 64 + l) * 16);
    f.ud1 = *(const u32x4*)(Udg + (tau * 256 + vs * 64 + l) * 16 + 8);
    f.opu = *(const u32x2*)(Opg + (tau * 256 + vs * 64 + l) * 4);
    f.ef = *(const f32x4*)(ECg + tau * 256 + l * 4);
    return f;
  };

  auto doChunk = [&](int c, const Frags& f) {
#pragma unroll
    for (int kt = 0; kt < 4; ++kt)
#pragma unroll
      for (int j = 0; j < 4; ++j) Sb[lq * 4 + j][kt * 16 + lr] = f2bf(S[kt][j]);
    bf16x8 a0 = *(const bf16x8*)&Sb[lr][lq * 8];
    bf16x8 a1 = *(const bf16x8*)&Sb[lr][32 + lq * 8];
    f32x4 s0b = {0.f, 0.f, 0.f, 0.f}, s0r = {0.f, 0.f, 0.f, 0.f};
    s0b = __builtin_amdgcn_mfma_f32_16x16x32_bf16(a0, f.m10, s0b, 0, 0, 0);
    s0b = __builtin_amdgcn_mfma_f32_16x16x32_bf16(a1, f.m11, s0b, 0, 0, 0);
    s0r = __builtin_amdgcn_mfma_f32_16x16x32_bf16(a0, f.m20, s0r, 0, 0, 0);
    s0r = __builtin_amdgcn_mfma_f32_16x16x32_bf16(a1, f.m21, s0r, 0, 0, 0);
#pragma unroll
    for (int j = 0; j < 4; ++j) negb[lq * 4 + j][lr] = f2bf(-s0b[j]);
    bf16x8 nb0 = *(const bf16x8*)&negb[lr][lq * 8];
    f32x4 o = __builtin_amdgcn_mfma_f32_16x16x32_bf16(nb0, f.g1b, s0r, 0, 0, 0);
    u16 op4[4];
    *(u32x2*)op4 = f.opu;
#pragma unroll
    for (int j = 0; j < 4; ++j) o[j] += bf2f(op4[j]);
    size_t orow = ((size_t)b * 1024 + c * 16 + lr) * 1024 + h * 64 + vs * 16 + lq * 4;
    *(f32x4*)(O + orow) = o;
    u16 udh[16];
    *(u32x4*)&udh[0] = f.ud0;
    *(u32x4*)&udh[8] = f.ud1;
    f32x4 cin0, cin1, cin2, cin3;
#pragma unroll
    for (int j = 0; j < 4; ++j) {
      cin0[j] = S[0][j] * f.ef[0] + bf2f(udh[0 * 4 + j]);
      cin1[j] = S[1][j] * f.ef[1] + bf2f(udh[1 * 4 + j]);
      cin2[j] = S[2][j] * f.ef[2] + bf2f(udh[2 * 4 + j]);
      cin3[j] = S[3][j] * f.ef[3] + bf2f(udh[3 * 4 + j]);
    }
    S[0] = __builtin_amdgcn_mfma_f32_16x16x32_bf16(nb0, f.g2b0, cin0, 0, 0, 0);
    S[1] = __builtin_amdgcn_mfma_f32_16x16x32_bf16(nb0, f.g2b1, cin1, 0, 0, 0);
    S[2] = __builtin_amdgcn_mfma_f32_16x16x32_bf16(nb0, f.g2b2, cin2, 0, 0, 0);
    S[3] = __builtin_amdgcn_mfma_f32_16x16x32_bf16(nb0, f.g2b3, cin3, 0, 0, 0);
  };

  Frags fA = loadF(0);
  Frags fB = loadF(1);
  for (int cp = 0; cp < 62; cp += 2) {
    doChunk(cp, fA);
    fA = loadF(cp + 2);
    doChunk(cp + 1, fB);
    fB = loadF(cp + 3);
  }
  doChunk(62, fA);
  doChunk(63, fB);
}

// ---------------- per-head groupnorm + bonus + gate -> bf16 (kp inline) ----------------
__global__ __launch_bounds__(256) void k_gn_gate(
    const float* __restrict__ O, const float* __restrict__ R,
    const float* __restrict__ KRAW, const float* __restrict__ Af,
    const float* __restrict__ ka_c,
    const float* __restrict__ V, const float* __restrict__ G,
    const float* __restrict__ r_k, const float* __restrict__ gn_w, const float* __restrict__ gn_b,
    u16* __restrict__ GT) {
  int row = blockIdx.x;
  int tid = threadIdx.x;
  int col = tid * 4;
  size_t idx = (size_t)row * Dd + col;
  f32x4 o = *(const f32x4*)(O + idx), r = *(const f32x4*)(R + idx),
        kr = *(const f32x4*)(KRAW + idx), av = *(const f32x4*)(Af + idx),
        v = *(const f32x4*)(V + idx), g = *(const f32x4*)(G + idx);
  f32x4 kac = *(const f32x4*)(ka_c + col);
  f32x4 rk = *(const f32x4*)(r_k + col), gw = *(const f32x4*)(gn_w + col),
        gb = *(const f32x4*)(gn_b + col);
  float so = 0, so2 = 0, sb = 0;
#pragma unroll
  for (int j = 0; j < 4; ++j) {
    float kp = kr[j] * (1.f + (av[j] - 1.f) * kac[j]);
    so += o[j]; so2 += o[j] * o[j]; sb += r[j] * kp * rk[j];
  }
#pragma unroll
  for (int m = 1; m < 16; m <<= 1) {
    so += __shfl_xor(so, m, 64);
    so2 += __shfl_xor(so2, m, 64);
    sb += __shfl_xor(sb, m, 64);
  }
  float mu = so * (1.f / 64.f);
  float var = so2 * (1.f / 64.f) - mu * mu;
  float rs = rsqrtf(var + 64e-5f);
#pragma unroll
  for (int j = 0; j < 4; ++j) {
    float on = (o[j] - mu) * rs * gw[j] + gb[j] + sb * v[j];
    GT[idx + j] = f2bf(on * g[j]);
  }
}

// ---------------- plain LN -> bf16 ----------------
__global__ __launch_bounds__(256) void k_ln(
    const float* __restrict__ X, const float* __restrict__ w, const float* __restrict__ bias,
    u16* __restrict__ OUT) {
  int row = blockIdx.x;
  int tid = threadIdx.x;
  int col = tid * 4;
  size_t idx = (size_t)row * Dd + col;
  f32x4 c = *(const f32x4*)(X + idx);
  float s1 = 0, s2 = 0;
#pragma unroll
  for (int j = 0; j < 4; ++j) { s1 += c[j]; s2 += c[j] * c[j]; }
#pragma unroll
  for (int m = 1; m < 64; m <<= 1) { s1 += __shfl_xor(s1, m, 64); s2 += __shfl_xor(s2, m, 64); }
  __shared__ float red[4][2];
  int wid = tid >> 6;
  if ((tid & 63) == 0) { red[wid][0] = s1; red[wid][1] = s2; }
  __syncthreads();
  s1 = red[0][0] + red[1][0] + red[2][0] + red[3][0];
  s2 = red[0][1] + red[1][1] + red[2][1] + red[3][1];
  const float invD = 1.f / (float)Dd;
  float mc = s1 * invD;
  float rc = rsqrtf(s2 * invD - mc * mc + 1e-5f);
#pragma unroll
  for (int j = 0; j < 4; ++j)
    OUT[idx + j] = f2bf((c[j] - mc) * rc * w[col + j] + bias[col + j]);
}

extern "C" void kernel_launch(void* const* d_in, const int* in_sizes, int n_in,
                              void* d_out, int out_size, void* d_ws, size_t ws_size,
                              hipStream_t stream) {
  const float* x    = (const float*)d_in[0];
  const float* ln1w = (const float*)d_in[1];
  const float* ln1b = (const float*)d_in[2];
  const float* ln2w = (const float*)d_in[3];
  const float* ln2b = (const float*)d_in[4];
  const float* xr_c = (const float*)d_in[5];
  const float* xw_c = (const float*)d_in[6];
  const float* xk_c = (const float*)d_in[7];
  const float* xv_c = (const float*)d_in[8];
  const float* xa_c = (const float*)d_in[9];
  const float* xg_c = (const float*)d_in[10];
  const float* Wr   = (const float*)d_in[11];
  const float* Wk   = (const float*)d_in[12];
  const float* Wv   = (const float*)d_in[13];
  const float* w0   = (const float*)d_in[14];
  const float* w1   = (const float*)d_in[15];
  const float* w2   = (const float*)d_in[16];
  const float* a0   = (const float*)d_in[17];
  const float* a1   = (const float*)d_in[18];
  const float* a2   = (const float*)d_in[19];
  const float* g1   = (const float*)d_in[20];
  const float* g2   = (const float*)d_in[21];
  const float* k_k  = (const float*)d_in[22];
  const float* k_a  = (const float*)d_in[23];
  const float* r_k  = (const float*)d_in[24];
  const float* gnw  = (const float*)d_in[25];
  const float* gnb  = (const float*)d_in[26];
  const float* Wo   = (const float*)d_in[27];
  const float* mlpw = (const float*)d_in[28];
  const float* mlpb = (const float*)d_in[29];

  char* ws = (char*)d_ws;
  const size_t MBy = 1024 * 1024;
  u16* WT_R  = (u16*)(ws + 0 * MBy);
  u16* WT_K  = (u16*)(ws + 2 * MBy);
  u16* WT_V  = (u16*)(ws + 4 * MBy);
  u16* WT_O  = (u16*)(ws + 6 * MBy);
  u16* WT_M  = (u16*)(ws + 8 * MBy);
  u16* WT_w1 = (u16*)(ws + 10 * MBy);
  u16* WT_a1 = (u16*)(ws + 10 * MBy + 128 * 1024);
  u16* WT_g1 = (u16*)(ws + 10 * MBy + 256 * 1024);
  u16* WT_w2 = (u16*)(ws + 10 * MBy + 512 * 1024);
  u16* WT_a2 = (u16*)(ws + 10 * MBy + 640 * 1024);
  u16* WT_g2 = (u16*)(ws + 10 * MBy + 768 * 1024);
  u16* XR = (u16*)(ws + 12 * MBy);
  u16* XW = (u16*)(ws + 20 * MBy);
  u16* XK = (u16*)(ws + 28 * MBy);
  u16* XV = (u16*)(ws + 36 * MBy);
  u16* XA = (u16*)(ws + 44 * MBy);
  u16* XG = (u16*)(ws + 52 * MBy);
  float* Rf    = (float*)(ws + 60 * MBy);
  float* KRAW  = (float*)(ws + 76 * MBy);
  float* WLOGf = (float*)(ws + 92 * MBy);
  float* Af    = (float*)(ws + 108 * MBy);
  float* Gf    = (float*)(ws + 124 * MBy);
  u16* HW = (u16*)(ws + 140 * MBy);
  u16* HA = (u16*)(ws + 140 * MBy + 512 * 1024);
  u16* HG = (u16*)(ws + 141 * MBy);
  // overlays
  float* Of   = (float*)(ws + 12 * MBy);   // over XR+XW (dead after QKV/lora1)
  float* X1   = (float*)(ws + 28 * MBy);   // over XK+XV (dead after QKV)
  u16* GT  = (u16*)(ws + 92 * MBy);        // over WLOGf (dead after k_chunk)
  u16* XN2 = (u16*)(ws + 116 * MBy);       // over Af upper half (dead after gn_gate)
  // chunked-scan tile arrays
  u16* TSg   = (u16*)(ws + 144 * MBy);
  u16* Udg   = (u16*)(ws + 188 * MBy);
  u16* Opg   = (u16*)(ws + 220 * MBy);
  float* ECg = (float*)(ws + 228 * MBy);
  float* OUT_X = (float*)d_out;
  float* OUT_V = (float*)d_out + (size_t)Mrows * Dd;

  dim3 blk(256);
  TransDesc td;
  td.src[0] = Wr;   td.dst[0] = WT_R;  td.K[0] = 1024; td.N[0] = 1024;
  td.src[1] = Wk;   td.dst[1] = WT_K;  td.K[1] = 1024; td.N[1] = 1024;
  td.src[2] = Wv;   td.dst[2] = WT_V;  td.K[2] = 1024; td.N[2] = 1024;
  td.src[3] = Wo;   td.dst[3] = WT_O;  td.K[3] = 1024; td.N[3] = 1024;
  td.src[4] = mlpw; td.dst[4] = WT_M;  td.K[4] = 1024; td.N[4] = 1024;
  td.src[5] = w1;   td.dst[5] = WT_w1; td.K[5] = 1024; td.N[5] = 64;
  td.src[6] = a1;   td.dst[6] = WT_a1; td.K[6] = 1024; td.N[6] = 64;
  td.src[7] = g1;   td.dst[7] = WT_g1; td.K[7] = 1024; td.N[7] = 128;
  td.src[8] = w2;   td.dst[8] = WT_w2; td.K[8] = 64;   td.N[8] = 1024;
  td.src[9] = a2;   td.dst[9] = WT_a2; td.K[9] = 64;   td.N[9] = 1024;
  td.src[10] = g2;  td.dst[10] = WT_g2; td.K[10] = 128; td.N[10] = 1024;
  k_transpose_all<<<dim3(32, 32, 11), blk, 0, stream>>>(td);

  k_ln_shift<<<Mrows, blk, 0, stream>>>(x, ln1w, ln1b, xr_c, xw_c, xk_c, xv_c, xa_c, xg_c,
                                        XR, XW, XK, XV, XA, XG);

  k_lora1<<<dim3(2, 32, 3), blk, 0, stream>>>(XW, XA, XG, WT_w1, WT_a1, WT_g1, HW, HA, HG);

  // merged QKV + second-stage LoRA: 6 homogeneous N=1024 GEMMs, 1536 wgs (6/CU)
  G6 g6;
  g6.A[0] = XR; g6.Bt[0] = WT_R;   g6.C[0] = Rf;    g6.aux[0] = nullptr; g6.K[0] = 1024; g6.epi[0] = 0;
  g6.A[1] = XK; g6.Bt[1] = WT_K;   g6.C[1] = KRAW;  g6.aux[1] = nullptr; g6.K[1] = 1024; g6.epi[1] = 0;
  g6.A[2] = XV; g6.Bt[2] = WT_V;   g6.C[2] = OUT_V; g6.aux[2] = nullptr; g6.K[2] = 1024; g6.epi[2] = 0;
  g6.A[3] = HW; g6.Bt[3] = WT_w2;  g6.C[3] = WLOGf; g6.aux[3] = w0;      g6.K[3] = 64;   g6.epi[3] = 4;
  g6.A[4] = HA; g6.Bt[4] = WT_a2;  g6.C[4] = Af;    g6.aux[4] = a0;      g6.K[4] = 64;   g6.epi[4] = 5;
  g6.A[5] = HG; g6.Bt[5] = WT_g2;  g6.C[5] = Gf;    g6.aux[5] = nullptr; g6.K[5] = 128;  g6.epi[5] = 0;
  k_gemm6<<<dim3(8, 32, 6), blk, 0, stream>>>(g6);

  k_chunk<<<4096, blk, 0, stream>>>(WLOGf, KRAW, Af, k_k, k_a, Rf, OUT_V, TSg, Opg, Udg, ECg);
  k_scan2<<<256, dim3(64), 0, stream>>>(TSg, Opg, Udg, ECg, Of);
  k_gn_gate<<<Mrows, blk, 0, stream>>>(Of, Rf, KRAW, Af, k_a, OUT_V, Gf, r_k, gnw, gnb, GT);
  k_gemm_bt<64, 128, 6, 64><<<dim3(8, 64), blk, 0, stream>>>(GT, WT_O, X1, nullptr, x, 1024, 1024);
  k_ln<<<Mrows, blk, 0, stream>>>(X1, ln2w, ln2b, XN2);
  k_gemm_bt<64, 128, 7, 64><<<dim3(8, 64), blk, 0, stream>>>(XN2, WT_M, OUT_X, mlpb, X1, 1024, 1024);
}